// Round 2
// baseline (28077.960 us; speedup 1.0000x reference)
//
#include <hip/hip_runtime.h>

#define NB 64
#define NT 1024
#define DIN 12
#define NH 256
#define NG 1024   // 4*H
#define NCLS 17
#define TC 128
#define NCHUNK 8

__device__ __forceinline__ float sigm(float v) { return 1.0f / (1.0f + __expf(-v)); }
__device__ __forceinline__ float tanh_(float v) {
    v = fminf(fmaxf(v, -15.0f), 15.0f);
    float e = __expf(2.0f * v);
    return (e - 1.0f) / (e + 1.0f);
}

// Map blockIdx so the 8 members of a clique (dir,bg) share one XCD
// (XCD = bid % 8 round-robin heuristic; correctness does not depend on it).
__device__ __forceinline__ void decode_bid(int bid, int& dir, int& bg, int& p) {
    int xcd = bid & 7, r = bid >> 3;   // r in [0,32)
    p = r & 7;
    int chi = r >> 3;                  // [0,4)
    int c = chi * 8 + xcd;             // clique [0,32)
    dir = c >> 4; bg = c & 15;
}

// ---------------------------------------------------------------------------
// k_rec<LAYER>: persistent-weight recurrence. Grid = 256 blocks x 256 thr.
// Block (dir, bg, p): owns hidden units [32p,32p+32) (=128 gate rows) for
// batches [4bg,4bg+4). Whh slice lives in VGPRs (128 floats/lane). Per step,
// the 256-float h of each batch is exchanged among the 8-block clique through
// an agent-coherent hbuf + monotonic flag counters.
// Wave w = k-quarter; lane l holds gates gl=l and gl=l+64 (gl = q*32+j).
// ---------------------------------------------------------------------------
template <int LAYER>
__global__ __launch_bounds__(256, 1) void k_rec(
    const float* __restrict__ w_hh,   // [2][1024][256] (this layer)
    const float* __restrict__ x,      // L0: [64][1024][12]
    const float* __restrict__ w_ih,   // L0: [2][1024][12]
    const float* __restrict__ b_ih, const float* __restrict__ b_hh,  // L0
    const float* __restrict__ xp1,    // L1: [2][64][TC][1024] (bias included)
    float* __restrict__ out0,         // L0 out: [64][1024][512]
    float* hbuf,                      // [32 clique][2 par][1024] (u*4+b)
    int* flags,                       // [32 clique][8]
    float* __restrict__ cstate, float* __restrict__ hsum,  // L1: [2][64][256]
    int base_step, int nsteps, int first) {

    __shared__ float hlds[NH * 4];      // [u][b]  4 KB
    __shared__ float part[4 * 4 * 128]; // [w][b][gl]  8 KB
    __shared__ float wih[128 * 13];     // L0 only (padded)
    __shared__ float xlds[4 * DIN];     // L0 only

    const int tid = threadIdx.x;
    int dir, bg, p; decode_bid(blockIdx.x, dir, bg, p);
    const int w = __builtin_amdgcn_readfirstlane(tid >> 6);
    const int l = tid & 63;
    const int q0 = l >> 5, j0 = l & 31;
    const int gate0 = q0 * NH + p * 32 + j0;        // q in {0,1}
    const int gate1 = (q0 + 2) * NH + p * 32 + j0;  // q in {2,3}
    const int clique = dir * 16 + bg;

    // ---- weight preload into VGPRs (one-time; w_hh stays L2-hot) ----
    float wreg0[64], wreg1[64];
    {
        const float4* r0 = (const float4*)(w_hh + ((size_t)dir * NG + gate0) * NH + 64 * w);
        const float4* r1 = (const float4*)(w_hh + ((size_t)dir * NG + gate1) * NH + 64 * w);
        #pragma unroll
        for (int kq = 0; kq < 16; ++kq) {
            float4 a = r0[kq];
            wreg0[4*kq+0]=a.x; wreg0[4*kq+1]=a.y; wreg0[4*kq+2]=a.z; wreg0[4*kq+3]=a.w;
            float4 b = r1[kq];
            wreg1[4*kq+0]=b.x; wreg1[4*kq+1]=b.y; wreg1[4*kq+2]=b.z; wreg1[4*kq+3]=b.w;
        }
    }

    // ---- act-thread persistent state (threads 0..127: (b_loc, j)) ----
    const int bloc = tid >> 5, j = tid & 31;   // valid for tid<128
    const int gb = 4 * bg + bloc;
    const int sidx = (dir * NB + gb) * NH + p * 32 + j;
    float cst = 0.f, hsv = 0.f;
    float bias0 = 0.f, bias1 = 0.f, bias2 = 0.f, bias3 = 0.f;
    if (tid < 128) {
        if (LAYER == 0) {
            bias0 = b_ih[dir*NG + 0*NH + p*32 + j] + b_hh[dir*NG + 0*NH + p*32 + j];
            bias1 = b_ih[dir*NG + 1*NH + p*32 + j] + b_hh[dir*NG + 1*NH + p*32 + j];
            bias2 = b_ih[dir*NG + 2*NH + p*32 + j] + b_hh[dir*NG + 2*NH + p*32 + j];
            bias3 = b_ih[dir*NG + 3*NH + p*32 + j] + b_hh[dir*NG + 3*NH + p*32 + j];
        } else if (!first) {
            cst = cstate[sidx];
            hsv = hsum[sidx];
        }
    }

    if (LAYER == 0) {
        for (int i = tid; i < 128 * DIN; i += 256) {
            int gl = i / DIN, d = i - gl * DIN;
            int q = gl >> 5, jj = gl & 31;
            wih[gl * 13 + d] = w_ih[((size_t)dir * NG + q * NH + p * 32 + jj) * DIN + d];
        }
    }

    // ---- hlds init: zeros (step 0) or previous chunk's h (parity 0) ----
    if (LAYER == 0 || first) {
        for (int i = tid; i < NH * 4; i += 256) hlds[i] = 0.f;
    } else {
        const float* slot0 = hbuf + (clique * 2 + 0) * (NH * 4);
        for (int i = tid; i < NH * 4; i += 256) hlds[i] = slot0[i];
    }
    __syncthreads();

    long spin_budget = 100000000;  // hang insurance; never hit in normal runs

    for (int it = 0; it < nsteps; ++it) {
        const int s = base_step + it;           // producing h_{s+1}
        const int t = (LAYER == 0) ? (dir ? (NT - 1 - it) : it) : it;

        // prefetch per-step gate inputs (latency overlapped with GEMM)
        float xq0 = 0.f, xq1 = 0.f, xq2 = 0.f, xq3 = 0.f;
        if (LAYER == 1 && tid < 128) {
            const float* xr = xp1 + (((size_t)dir * NB + gb) * TC + it) * NG + p * 32 + j;
            xq0 = xr[0]; xq1 = xr[NH]; xq2 = xr[2 * NH]; xq3 = xr[3 * NH];
        }
        if (LAYER == 0 && tid < 4 * DIN) {
            int bb = tid / DIN, d = tid - bb * DIN;
            xlds[tid] = x[((size_t)(4 * bg + bb) * NT + t) * DIN + d];
        }

        // ---- GEMM: 2 gates x 4 batches x 64 k (quarter) from registers ----
        float a00=0,a01=0,a02=0,a03=0, a10=0,a11=0,a12=0,a13=0;
        const float4* h4 = (const float4*)hlds;
        #pragma unroll
        for (int kk = 0; kk < 64; ++kk) {
            float4 hb = h4[64 * w + kk];          // wave-uniform -> broadcast
            float w0 = wreg0[kk], w1 = wreg1[kk];
            a00 += w0 * hb.x; a01 += w0 * hb.y; a02 += w0 * hb.z; a03 += w0 * hb.w;
            a10 += w1 * hb.x; a11 += w1 * hb.y; a12 += w1 * hb.z; a13 += w1 * hb.w;
        }
        part[(w * 4 + 0) * 128 + l] = a00;
        part[(w * 4 + 1) * 128 + l] = a01;
        part[(w * 4 + 2) * 128 + l] = a02;
        part[(w * 4 + 3) * 128 + l] = a03;
        part[(w * 4 + 0) * 128 + 64 + l] = a10;
        part[(w * 4 + 1) * 128 + 64 + l] = a11;
        part[(w * 4 + 2) * 128 + 64 + l] = a12;
        part[(w * 4 + 3) * 128 + 64 + l] = a13;
        __syncthreads();  // B1: partials + xlds ready; hlds reads done

        // ---- reduce + activation (threads 0..127) ----
        float* slot = hbuf + (clique * 2 + ((s + 1) & 1)) * (NH * 4);
        if (tid < 128) {
            float z[4];
            #pragma unroll
            for (int q = 0; q < 4; ++q) {
                z[q] = part[(0 * 4 + bloc) * 128 + q * 32 + j]
                     + part[(1 * 4 + bloc) * 128 + q * 32 + j]
                     + part[(2 * 4 + bloc) * 128 + q * 32 + j]
                     + part[(3 * 4 + bloc) * 128 + q * 32 + j];
            }
            if (LAYER == 0) {
                z[0] += bias0; z[1] += bias1; z[2] += bias2; z[3] += bias3;
                #pragma unroll
                for (int q = 0; q < 4; ++q) {
                    float acc = 0.f;
                    #pragma unroll
                    for (int d = 0; d < DIN; ++d)
                        acc += wih[(q * 32 + j) * 13 + d] * xlds[bloc * DIN + d];
                    z[q] += acc;
                }
            } else {
                z[0] += xq0; z[1] += xq1; z[2] += xq2; z[3] += xq3;
            }
            float ig = sigm(z[0]), fg = sigm(z[1]), gg = tanh_(z[2]), og = sigm(z[3]);
            cst = fg * cst + ig * gg;
            float hval = og * tanh_(cst);
            if (LAYER == 1) hsv += hval;
            hlds[(p * 32 + j) * 4 + bloc] = hval;
            __hip_atomic_store(&slot[(p * 32 + j) * 4 + bloc], hval,
                               __ATOMIC_RELAXED, __HIP_MEMORY_SCOPE_AGENT);
            if (LAYER == 0)
                out0[((size_t)gb * NT + t) * (2 * NH) + dir * NH + p * 32 + j] = hval;
        }
        __syncthreads();  // B3: all publishes issued & drained (vmcnt(0) at barrier)

        if (tid == 0) {
            __threadfence();
            __hip_atomic_store(&flags[clique * 8 + p], s + 1,
                               __ATOMIC_RELEASE, __HIP_MEMORY_SCOPE_AGENT);
        }
        if (tid >= 128 && tid < 136) {
            const int fi = clique * 8 + (tid - 128);
            while (__hip_atomic_load(&flags[fi], __ATOMIC_ACQUIRE,
                                     __HIP_MEMORY_SCOPE_AGENT) < s + 1) {
                __builtin_amdgcn_s_sleep(1);
                if (--spin_budget < 0) break;
            }
        }
        __syncthreads();  // B4: all 8 clique members published h_{s+1}

        #pragma unroll
        for (int i2 = 0; i2 < 4; ++i2) {
            float v = __hip_atomic_load(&slot[tid + 256 * i2],
                                        __ATOMIC_RELAXED, __HIP_MEMORY_SCOPE_AGENT);
            hlds[tid + 256 * i2] = v;
        }
        __syncthreads();  // B5: hlds = h_{s+1}
    }

    if (LAYER == 1 && tid < 128) {
        cstate[sidx] = cst;
        hsum[sidx] = hsv;
    }
}

// ---------------------------------------------------------------------------
// k_proj: xp1[dir][b][tl][g] = out0[b][t(tl)][:512] . w_ih1[dir][g][:512] + biases
// fp32 tiled GEMM, 64x64 tile, 256 threads, 4x4 micro-tile, K-step 16.
// ---------------------------------------------------------------------------
#define KT 16
#define LDP 68

__launch_bounds__(256)
__global__ void k_proj(const float* __restrict__ out0, const float* __restrict__ w_ih1,
                       const float* __restrict__ b_ih1, const float* __restrict__ b_hh1,
                       float* __restrict__ xp1, int chunk) {
    __shared__ float Als[KT * LDP];
    __shared__ float Bls[KT * LDP];

    const int tid = threadIdx.x;
    const int rowbase = blockIdx.x * 64;
    const int colbase = blockIdx.y * 64;
    const int dir = blockIdx.z;

    const int lm = tid >> 2;
    const int kq = tid & 3;

    const int r  = rowbase + lm;
    const int ab = r >> 7;
    const int tl = r & 127;
    const int t  = dir ? (NT - 1 - chunk * TC - tl) : (chunk * TC + tl);
    const float* arow = out0 + (size_t)(ab * NT + t) * (2 * NH);
    const int gg = colbase + lm;
    const float* brow = w_ih1 + (size_t)(dir * NG + gg) * (2 * NH);

    const int tx = tid & 15;
    const int ty = tid >> 4;

    float acc[4][4];
    #pragma unroll
    for (int q = 0; q < 4; ++q)
        #pragma unroll
        for (int pp = 0; pp < 4; ++pp) acc[q][pp] = 0.0f;

    const float4* Als4 = (const float4*)Als;
    const float4* Bls4 = (const float4*)Bls;

    for (int k0 = 0; k0 < 2 * NH; k0 += KT) {
        float4 av = ((const float4*)(arow + k0))[kq];
        float4 bv = ((const float4*)(brow + k0))[kq];
        __syncthreads();
        Als[(kq * 4 + 0) * LDP + lm] = av.x;
        Als[(kq * 4 + 1) * LDP + lm] = av.y;
        Als[(kq * 4 + 2) * LDP + lm] = av.z;
        Als[(kq * 4 + 3) * LDP + lm] = av.w;
        Bls[(kq * 4 + 0) * LDP + lm] = bv.x;
        Bls[(kq * 4 + 1) * LDP + lm] = bv.y;
        Bls[(kq * 4 + 2) * LDP + lm] = bv.z;
        Bls[(kq * 4 + 3) * LDP + lm] = bv.w;
        __syncthreads();
        #pragma unroll
        for (int kk = 0; kk < KT; ++kk) {
            float4 a4 = Als4[kk * (LDP / 4) + ty];
            float4 b4 = Bls4[kk * (LDP / 4) + tx];
            acc[0][0] += a4.x * b4.x; acc[0][1] += a4.x * b4.y; acc[0][2] += a4.x * b4.z; acc[0][3] += a4.x * b4.w;
            acc[1][0] += a4.y * b4.x; acc[1][1] += a4.y * b4.y; acc[1][2] += a4.y * b4.z; acc[1][3] += a4.y * b4.w;
            acc[2][0] += a4.z * b4.x; acc[2][1] += a4.z * b4.y; acc[2][2] += a4.z * b4.z; acc[2][3] += a4.z * b4.w;
            acc[3][0] += a4.w * b4.x; acc[3][1] += a4.w * b4.y; acc[3][2] += a4.w * b4.z; acc[3][3] += a4.w * b4.w;
        }
    }

    const int col = colbase + tx * 4;
    float4 bias;
    bias.x = b_ih1[dir * NG + col + 0] + b_hh1[dir * NG + col + 0];
    bias.y = b_ih1[dir * NG + col + 1] + b_hh1[dir * NG + col + 1];
    bias.z = b_ih1[dir * NG + col + 2] + b_hh1[dir * NG + col + 2];
    bias.w = b_ih1[dir * NG + col + 3] + b_hh1[dir * NG + col + 3];
    #pragma unroll
    for (int q = 0; q < 4; ++q) {
        const int rr = rowbase + ty * 4 + q;
        const int ob = rr >> 7, otl = rr & 127;
        float4 v;
        v.x = acc[q][0] + bias.x;
        v.y = acc[q][1] + bias.y;
        v.z = acc[q][2] + bias.z;
        v.w = acc[q][3] + bias.w;
        *(float4*)(xp1 + ((size_t)((dir * NB + ob) * TC + otl)) * NG + col) = v;
    }
}

// ---------------------------------------------------------------------------
__global__ void k_fc(const float* __restrict__ hsum, const float* __restrict__ fc_w,
                     const float* __restrict__ fc_b, float* __restrict__ out) {
    const int b = blockIdx.x;
    const int n = threadIdx.x;
    if (n >= NCLS) return;
    float acc = fc_b[n];
    const float inv = 1.0f / (float)NT;
    for (int k = 0; k < 2 * NH; ++k) {
        float pv = hsum[((k >> 8) * NB + b) * NH + (k & 255)];
        acc += (pv * inv) * fc_w[n * 2 * NH + k];
    }
    out[b * NCLS + n] = acc;
}

// ---------------------------------------------------------------------------
extern "C" void kernel_launch(void* const* d_in, const int* in_sizes, int n_in,
                              void* d_out, int out_size, void* d_ws, size_t ws_size,
                              hipStream_t stream) {
    const float* x     = (const float*)d_in[0];
    const float* w_ih0 = (const float*)d_in[1];
    const float* w_hh0 = (const float*)d_in[2];
    const float* b_ih0 = (const float*)d_in[3];
    const float* b_hh0 = (const float*)d_in[4];
    const float* w_ih1 = (const float*)d_in[5];
    const float* w_hh1 = (const float*)d_in[6];
    const float* b_ih1 = (const float*)d_in[7];
    const float* b_hh1 = (const float*)d_in[8];
    const float* fc_w  = (const float*)d_in[9];
    const float* fc_b  = (const float*)d_in[10];
    float* out = (float*)d_out;

    float* ws = (float*)d_ws;
    float* hbuf0  = ws;                                // 32*2*1024 = 65536
    float* hbuf1  = hbuf0 + 65536;                     // 65536
    int*   flags0 = (int*)(hbuf1 + 65536);             // 256 ints
    int*   flags1 = flags0 + 256;                      // 256 ints
    float* out0   = (float*)(flags1 + 256);            // [64][1024][512]
    float* xp1    = out0 + (size_t)NB * NT * 2 * NH;   // [2][64][128][1024]
    float* cstate = xp1 + (size_t)2 * NB * TC * NG;    // [2][64][256]
    float* hsum   = cstate + 2 * NB * NH;              // [2][64][256]

    hipMemsetAsync(flags0, 0, 512 * sizeof(int), stream);

    k_rec<0><<<dim3(256), dim3(256), 0, stream>>>(
        w_hh0, x, w_ih0, b_ih0, b_hh0, nullptr,
        out0, hbuf0, flags0, nullptr, nullptr, 0, NT, 1);

    for (int c = 0; c < NCHUNK; ++c) {
        k_proj<<<dim3(128, 16, 2), dim3(256), 0, stream>>>(
            out0, w_ih1, b_ih1, b_hh1, xp1, c);
        k_rec<1><<<dim3(256), dim3(256), 0, stream>>>(
            w_hh1, nullptr, nullptr, nullptr, nullptr, xp1,
            nullptr, hbuf1, flags1, cstate, hsum, c * TC, TC, (c == 0) ? 1 : 0);
    }

    k_fc<<<dim3(64), dim3(32), 0, stream>>>(hsum, fc_w, fc_b, out);
}

// Round 5
// 13194.952 us; speedup vs baseline: 2.1279x; 2.1279x over previous
//
#include <hip/hip_runtime.h>

#define NB 64
#define NT 1024
#define DIN 12
#define NH 256
#define NG 1024
#define NCLS 17
#define TC 64
#define NCHUNK 16

typedef _Float16 f16;
typedef __attribute__((ext_vector_type(2))) _Float16 half2_t;
typedef unsigned int uint;

__device__ __forceinline__ float sigm(float v) { return 1.0f / (1.0f + __expf(-v)); }
__device__ __forceinline__ float tanh_(float v) {
    v = fminf(fmaxf(v, -15.0f), 15.0f);
    float e = __expf(2.0f * v);
    return (e - 1.0f) / (e + 1.0f);
}
__device__ __forceinline__ float dot2(uint w, uint h, float c) {
    return __builtin_amdgcn_fdot2(__builtin_bit_cast(half2_t, w),
                                  __builtin_bit_cast(half2_t, h), c, false);
}
__device__ __forceinline__ uint pack16(float a, float b) {
    union { f16 h[2]; uint u; } cv; cv.h[0] = (f16)a; cv.h[1] = (f16)b; return cv.u;
}
__device__ __forceinline__ uint pkrtz(float a, float b) {
    return __builtin_bit_cast(uint, __builtin_amdgcn_cvt_pkrtz(a, b));
}
__device__ __forceinline__ unsigned short hbits(f16 v) {
    union { f16 h; unsigned short u; } cv; cv.h = v; return cv.u;
}

// ---------------------------------------------------------------------------
// k_prep: pack fp16 weights. ld = layer*2+dir.
//  Wkr [ld][q][t][kp 0..87]  (VGPR part, kp fastest -> per-lane uint4 loads)
//  Wkl [ld][q][kk 0..7][t]   (LDS part, kp=88+kk, t fastest -> conflict-free)
//  Wst [ld][grp 0..7][q][t]  uint4 (streamed part, kp=96+4grp+j, coalesced)
//  wih0p [dir][q][dp 0..5][t] packed half2 of w_ih0 input pairs
//  wih1h fp16 copy of w_ih1; bsum1 = b_ih1+b_hh1
// ---------------------------------------------------------------------------
__global__ void k_prep(const float* __restrict__ w_hh0, const float* __restrict__ w_hh1,
                       const float* __restrict__ w_ih0, const float* __restrict__ w_ih1,
                       const float* __restrict__ b_ih1, const float* __restrict__ b_hh1,
                       uint* __restrict__ Wkr, uint* __restrict__ Wkl,
                       uint* __restrict__ Wst, uint* __restrict__ wih0p,
                       f16* __restrict__ wih1h, float* __restrict__ bsum1) {
    int i = blockIdx.x * 256 + threadIdx.x;
    if (i < 4 * 4 * 256 * 88) {
        int kp = i % 88; int r = i / 88;
        int t = r & 255, q = (r >> 8) & 3, ld = r >> 10;
        const float* row = (ld < 2 ? w_hh0 : w_hh1) + (size_t)(ld & 1) * NG * NH
                         + (size_t)(q * 256 + t) * NH;
        Wkr[i] = pack16(row[2 * kp], row[2 * kp + 1]);
    }
    if (i < 4 * 4 * 8 * 256) {
        int t = i & 255; int r = i >> 8;
        int kk = r & 7, q = (r >> 3) & 3, ld = r >> 5;
        const float* row = (ld < 2 ? w_hh0 : w_hh1) + (size_t)(ld & 1) * NG * NH
                         + (size_t)(q * 256 + t) * NH;
        Wkl[i] = pack16(row[2 * (88 + kk)], row[2 * (88 + kk) + 1]);
    }
    if (i < 4 * 8 * 4 * 256 * 4) {
        int j = i & 3; int u = i >> 2;
        int t = u & 255; int r = u >> 8;
        int q = r & 3, grp = (r >> 2) & 7, ld = r >> 5;
        int kp = 96 + 4 * grp + j;
        const float* row = (ld < 2 ? w_hh0 : w_hh1) + (size_t)(ld & 1) * NG * NH
                         + (size_t)(q * 256 + t) * NH;
        Wst[i] = pack16(row[2 * kp], row[2 * kp + 1]);
    }
    if (i < 2 * 4 * 6 * 256) {
        int t = i & 255; int r = i >> 8;
        int dp = r % 6, q = (r / 6) & 3, dd = r / 24;
        const float* row = w_ih0 + ((size_t)dd * NG + q * 256 + t) * DIN;
        wih0p[i] = pack16(row[2 * dp], row[2 * dp + 1]);
    }
    if (i < 2 * NG * 2 * NH) wih1h[i] = (f16)w_ih1[i];
    if (i < 2 * NG) bsum1[i] = b_ih1[i] + b_hh1[i];
}

// ---------------------------------------------------------------------------
// rec_seq<LAYER>: one block per (dir, batch), 256 threads. Lane t owns unit t
// (gate rows t, 256+t, 512+t, 768+t). Whh fp16: 352 VGPR + 32 KB LDS resident,
// 128 KB/step streamed from L2. h carried fp32, fed to fdot2 as hi+lo fp16
// split. One __syncthreads per step; no inter-block communication.
// ---------------------------------------------------------------------------
#define VG(g) { uint4 Hhv = Hh[g], Hlv = Hl[g];                                   \
    _Pragma("unroll") for (int q = 0; q < 4; ++q) { uint4 w = wr[q][g];           \
        ah[q] = dot2(w.x, Hhv.x, ah[q]); al[q] = dot2(w.x, Hlv.x, al[q]);         \
        ah[q] = dot2(w.y, Hhv.y, ah[q]); al[q] = dot2(w.y, Hlv.y, al[q]);         \
        ah[q] = dot2(w.z, Hhv.z, ah[q]); al[q] = dot2(w.z, Hlv.z, al[q]);         \
        ah[q] = dot2(w.w, Hhv.w, ah[q]); al[q] = dot2(w.w, Hlv.w, al[q]); } }

#define SG(s) { uint4 Hhv = Hh[24 + (s)], Hlv = Hl[24 + (s)];                     \
    _Pragma("unroll") for (int q = 0; q < 4; ++q) {                               \
        uint4 w = ((s) & 1) ? sb1[q] : sb0[q];                                    \
        ah[q] = dot2(w.x, Hhv.x, ah[q]); al[q] = dot2(w.x, Hlv.x, al[q]);         \
        ah[q] = dot2(w.y, Hhv.y, ah[q]); al[q] = dot2(w.y, Hlv.y, al[q]);         \
        ah[q] = dot2(w.z, Hhv.z, ah[q]); al[q] = dot2(w.z, Hlv.z, al[q]);         \
        ah[q] = dot2(w.w, Hhv.w, ah[q]); al[q] = dot2(w.w, Hlv.w, al[q]); }       \
    if ((s) + 2 < 8) { _Pragma("unroll") for (int q = 0; q < 4; ++q) {            \
        uint4 nv = WsB[(((s) + 2) * 4 + q) * 256 + tid];                          \
        if ((s) & 1) sb1[q] = nv; else sb0[q] = nv; } } }

#define LG(k2) { uint4 Hhv = Hh[22 + (k2)], Hlv = Hl[22 + (k2)];                  \
    _Pragma("unroll") for (int q = 0; q < 4; ++q) {                               \
        uint w0 = wlds[(q * 8 + (k2) * 4 + 0) * 256 + tid];                       \
        uint w1 = wlds[(q * 8 + (k2) * 4 + 1) * 256 + tid];                       \
        uint w2 = wlds[(q * 8 + (k2) * 4 + 2) * 256 + tid];                       \
        uint w3 = wlds[(q * 8 + (k2) * 4 + 3) * 256 + tid];                       \
        ah[q] = dot2(w0, Hhv.x, ah[q]); al[q] = dot2(w0, Hlv.x, al[q]);           \
        ah[q] = dot2(w1, Hhv.y, ah[q]); al[q] = dot2(w1, Hlv.y, al[q]);           \
        ah[q] = dot2(w2, Hhv.z, ah[q]); al[q] = dot2(w2, Hlv.z, al[q]);           \
        ah[q] = dot2(w3, Hhv.w, ah[q]); al[q] = dot2(w3, Hlv.w, al[q]); } }

template <int LAYER>
__device__ void rec_seq(char* smem, int rb, int chunk, int nsteps,
                        const uint* __restrict__ Wkr, const uint* __restrict__ Wkl,
                        const uint4* __restrict__ Wst, const uint* __restrict__ wih0p,
                        const float* __restrict__ b_ih0, const float* __restrict__ b_hh0,
                        const float* __restrict__ x, const float* __restrict__ xp1par,
                        f16* __restrict__ out0h,
                        float* __restrict__ hst, float* __restrict__ cst,
                        float* __restrict__ hsm) {
    uint* wlds = (uint*)smem;                                   // [4][8][256] 32 KB
    unsigned short* hs16 = (unsigned short*)(smem + 32768);     // [2][2][256] 2 KB
    uint* wihl = (uint*)(smem + 32768 + 2048);                  // [4][6][256] 24 KB

    const int tid = threadIdx.x;
    const int dir = rb >> 6;
    const int b = rb & 63;
    const int ld = LAYER * 2 + dir;

    for (int n = tid; n < 8192; n += 256) wlds[n] = Wkl[ld * 8192 + n];
    if (LAYER == 0)
        for (int n = tid; n < 6144; n += 256) wihl[n] = wih0p[dir * 6144 + n];

    uint4 wr[4][22];
    #pragma unroll
    for (int q = 0; q < 4; ++q) {
        const uint4* src = (const uint4*)(Wkr + (size_t)((ld * 4 + q) * 256 + tid) * 88);
        #pragma unroll
        for (int m = 0; m < 22; ++m) wr[q][m] = src[m];
    }

    float bias[4] = {0.f, 0.f, 0.f, 0.f};
    if (LAYER == 0) {
        #pragma unroll
        for (int q = 0; q < 4; ++q)
            bias[q] = b_ih0[dir * NG + q * 256 + tid] + b_hh0[dir * NG + q * 256 + tid];
    }

    const int sidx = (ld * NB + b) * NH + tid;
    float cv, hv, hsv = 0.f;
    if (chunk == 0) { cv = 0.f; hv = 0.f; }
    else {
        cv = cst[sidx]; hv = hst[sidx];
        if (LAYER == 1) hsv = hsm[(dir * NB + b) * NH + tid];
    }
    {
        f16 hi = (f16)hv, lo = (f16)(hv - (float)hi);
        hs16[tid] = hbits(hi); hs16[256 + tid] = hbits(lo);
    }
    const uint4* WsB = Wst + (size_t)ld * (8 * 4 * 256);
    __syncthreads();

    #pragma unroll 1
    for (int it = 0; it < nsteps; ++it) {
        const int par = it & 1;
        const uint4* Hh = (const uint4*)(hs16 + par * 512);
        const uint4* Hl = (const uint4*)(hs16 + par * 512 + 256);

        float ah[4] = {0, 0, 0, 0}, al[4] = {0, 0, 0, 0};
        uint4 sb0[4], sb1[4];
        #pragma unroll
        for (int q = 0; q < 4; ++q) sb0[q] = WsB[(0 * 4 + q) * 256 + tid];
        #pragma unroll
        for (int q = 0; q < 4; ++q) sb1[q] = WsB[(1 * 4 + q) * 256 + tid];

        float xv[12]; float xq[4];
        if (LAYER == 0) {
            const int t = dir ? (NT - 1 - it) : it;   // L0 runs full pass (chunk 0)
            const float4* xp = (const float4*)(x + ((size_t)b * NT + t) * DIN);
            float4 A = xp[0], B4 = xp[1], C4 = xp[2];
            xv[0] = A.x;  xv[1] = A.y;  xv[2] = A.z;  xv[3] = A.w;
            xv[4] = B4.x; xv[5] = B4.y; xv[6] = B4.z; xv[7] = B4.w;
            xv[8] = C4.x; xv[9] = C4.y; xv[10] = C4.z; xv[11] = C4.w;
        } else {
            const float* p = xp1par + (((size_t)dir * NB + b) * TC + it) * NG + tid;
            #pragma unroll
            for (int q = 0; q < 4; ++q) xq[q] = p[q * 256];
        }

        VG(0)  VG(1)  VG(2)  SG(0)
        VG(3)  VG(4)  VG(5)  SG(1)
        VG(6)  VG(7)  VG(8)  SG(2)
        VG(9)  VG(10) VG(11) SG(3)
        VG(12) VG(13) VG(14) SG(4)
        VG(15) VG(16) VG(17) SG(5)
        VG(18) VG(19)        SG(6)
        VG(20) VG(21)        SG(7)
        LG(0)  LG(1)

        float z[4];
        #pragma unroll
        for (int q = 0; q < 4; ++q) z[q] = ah[q] + al[q];
        if (LAYER == 0) {
            uint xph[6];
            #pragma unroll
            for (int d = 0; d < 6; ++d) xph[d] = pkrtz(xv[2 * d], xv[2 * d + 1]);
            #pragma unroll
            for (int q = 0; q < 4; ++q) {
                float a = bias[q];
                #pragma unroll
                for (int d = 0; d < 6; ++d)
                    a = dot2(wihl[(q * 6 + d) * 256 + tid], xph[d], a);
                z[q] += a;
            }
        } else {
            #pragma unroll
            for (int q = 0; q < 4; ++q) z[q] += xq[q];
        }
        cv = sigm(z[1]) * cv + sigm(z[0]) * tanh_(z[2]);
        hv = sigm(z[3]) * tanh_(cv);
        if (LAYER == 1) hsv += hv;

        f16 hi = (f16)hv, lo = (f16)(hv - (float)hi);
        unsigned short* wo = hs16 + (par ^ 1) * 512;
        wo[tid] = hbits(hi); wo[256 + tid] = hbits(lo);
        if (LAYER == 0) {
            const int t = dir ? (NT - 1 - it) : it;
            out0h[((size_t)b * NT + t) * 512 + dir * 256 + tid] = hi;
        }
        __syncthreads();
    }

    cst[sidx] = cv; hst[sidx] = hv;
    if (LAYER == 1) hsm[(dir * NB + b) * NH + tid] = hsv;
}

// ---------------------------------------------------------------------------
// proj_role: xp1[dir][b][tl][g] = out0h[b][t][0:512] . wih1h[dir][g][0:512]
//            + bsum1. fp16 fdot2 / fp32 acc, 64x64 tiles, 16 tiles/block.
// Valid because phase A (all of L0) completed before any proj launch.
// ---------------------------------------------------------------------------
__device__ void proj_role(char* smem, int pb, int c,
                          const f16* __restrict__ out0h, const f16* __restrict__ wih1h,
                          const float* __restrict__ bsum1, float* __restrict__ xp1par) {
    uint* AU = (uint*)smem;            // [16][68]
    uint* BU = AU + 16 * 68;

    const int tid = threadIdx.x;
    const int row = tid >> 2, kq = tid & 3;
    const int tx = tid & 15, ty = tid >> 4;

    for (int i = 0; i < 16; ++i) {
        const int tile = pb * 16 + i;          // 2048 tiles: dir(1) x rt(6b) x ct(4b)
        const int dirt = tile >> 10;
        const int rt = (tile >> 4) & 63;
        const int ct = tile & 15;

        const int r = rt * 64 + row;           // over 4096 rows = b(64) x tl(64)
        const int ab = r >> 6, tl = r & 63;
        const int t = dirt ? (NT - 1 - c * TC - tl) : (c * TC + tl);
        const uint4* Ap = (const uint4*)(out0h + ((size_t)ab * NT + t) * 512);
        const uint4* Bp = (const uint4*)(wih1h + (size_t)(dirt * NG + ct * 64 + row) * 512);

        float acc[4][4];
        #pragma unroll
        for (int q = 0; q < 4; ++q)
            #pragma unroll
            for (int p = 0; p < 4; ++p) acc[q][p] = 0.f;

        for (int k0 = 0; k0 < 64; k0 += 4) {
            uint4 av = Ap[k0 + kq];
            uint4 bv = Bp[k0 + kq];
            __syncthreads();
            AU[(kq * 4 + 0) * 68 + row] = av.x; AU[(kq * 4 + 1) * 68 + row] = av.y;
            AU[(kq * 4 + 2) * 68 + row] = av.z; AU[(kq * 4 + 3) * 68 + row] = av.w;
            BU[(kq * 4 + 0) * 68 + row] = bv.x; BU[(kq * 4 + 1) * 68 + row] = bv.y;
            BU[(kq * 4 + 2) * 68 + row] = bv.z; BU[(kq * 4 + 3) * 68 + row] = bv.w;
            __syncthreads();
            #pragma unroll
            for (int kp = 0; kp < 16; ++kp) {
                uint4 a4 = *(const uint4*)&AU[kp * 68 + ty * 4];
                uint4 b4 = *(const uint4*)&BU[kp * 68 + tx * 4];
                uint aa[4] = {a4.x, a4.y, a4.z, a4.w};
                uint bb[4] = {b4.x, b4.y, b4.z, b4.w};
                #pragma unroll
                for (int q = 0; q < 4; ++q)
                    #pragma unroll
                    for (int p = 0; p < 4; ++p)
                        acc[q][p] = dot2(aa[q], bb[p], acc[q][p]);
            }
        }

        const int col = ct * 64 + tx * 4;
        float4 bias = *(const float4*)&bsum1[dirt * NG + col];
        #pragma unroll
        for (int q = 0; q < 4; ++q) {
            const int rr = rt * 64 + ty * 4 + q;
            const int ob = rr >> 6, otl = rr & 63;
            float4 v = make_float4(acc[q][0] + bias.x, acc[q][1] + bias.y,
                                   acc[q][2] + bias.z, acc[q][3] + bias.w);
            *(float4*)(xp1par + ((size_t)(dirt * NB + ob) * TC + otl) * NG + col) = v;
        }
    }
}

// ---------------------------------------------------------------------------
// Phase A: layer 0, full 1024 steps, 128 independent blocks.
// ---------------------------------------------------------------------------
__global__ __launch_bounds__(256, 1) void k_rec0(
    const uint* __restrict__ Wkr, const uint* __restrict__ Wkl,
    const uint4* __restrict__ Wst, const uint* __restrict__ wih0p,
    const float* __restrict__ b_ih0, const float* __restrict__ b_hh0,
    const float* __restrict__ x, f16* __restrict__ out0h,
    float* __restrict__ hst, float* __restrict__ cst) {
    __shared__ __align__(16) char smem[59392];
    rec_seq<0>(smem, blockIdx.x, 0, NT, Wkr, Wkl, Wst, wih0p, b_ih0, b_hh0,
               x, nullptr, out0h, hst, cst, nullptr);
}

// ---------------------------------------------------------------------------
// Phase B launch j: blocks 0..127 = L1 chunk j-1; blocks 128..255 = proj chunk j.
// ---------------------------------------------------------------------------
#define XPS ((size_t)2 * NB * TC * NG)

__global__ __launch_bounds__(256, 1) void k_pipe(
    int j,
    const uint* __restrict__ Wkr, const uint* __restrict__ Wkl,
    const uint4* __restrict__ Wst,
    const f16* __restrict__ out0h, const f16* __restrict__ wih1h,
    const float* __restrict__ bsum1, float* __restrict__ xp1,
    float* __restrict__ hst, float* __restrict__ cst, float* __restrict__ hsm) {
    __shared__ __align__(16) char smem[59392];
    const int bid = blockIdx.x;
    if (bid < 128) {
        const int cc = j - 1;
        if (cc >= 0 && cc < NCHUNK)
            rec_seq<1>(smem, bid, cc, TC, Wkr, Wkl, Wst, nullptr, nullptr, nullptr,
                       nullptr, xp1 + (size_t)(cc & 1) * XPS, nullptr, hst, cst, hsm);
    } else {
        const int cp = j;
        if (cp < NCHUNK)
            proj_role(smem, bid - 128, cp, out0h, wih1h, bsum1,
                      xp1 + (size_t)(cp & 1) * XPS);
    }
}

// ---------------------------------------------------------------------------
__global__ void k_fc(const float* __restrict__ hsm, const float* __restrict__ fc_w,
                     const float* __restrict__ fc_b, float* __restrict__ out) {
    const int b = blockIdx.x;
    const int n = threadIdx.x;
    if (n >= NCLS) return;
    float acc = fc_b[n];
    const float inv = 1.0f / (float)NT;
    for (int k = 0; k < 2 * NH; ++k) {
        float pv = hsm[((k >> 8) * NB + b) * NH + (k & 255)];
        acc += (pv * inv) * fc_w[n * 2 * NH + k];
    }
    out[b * NCLS + n] = acc;
}

// ---------------------------------------------------------------------------
extern "C" void kernel_launch(void* const* d_in, const int* in_sizes, int n_in,
                              void* d_out, int out_size, void* d_ws, size_t ws_size,
                              hipStream_t stream) {
    const float* x     = (const float*)d_in[0];
    const float* w_ih0 = (const float*)d_in[1];
    const float* w_hh0 = (const float*)d_in[2];
    const float* b_ih0 = (const float*)d_in[3];
    const float* b_hh0 = (const float*)d_in[4];
    const float* w_ih1 = (const float*)d_in[5];
    const float* w_hh1 = (const float*)d_in[6];
    const float* b_ih1 = (const float*)d_in[7];
    const float* b_hh1 = (const float*)d_in[8];
    const float* fc_w  = (const float*)d_in[9];
    const float* fc_b  = (const float*)d_in[10];
    float* out = (float*)d_out;

    char* ws = (char*)d_ws;
    uint* Wkr   = (uint*)ws;                      // 360448 u
    uint* Wkl   = Wkr + 360448;                   // 32768 u
    uint* Wst   = Wkl + 32768;                    // 131072 u
    uint* wih0p = Wst + 131072;                   // 12288 u
    f16* wih1h  = (f16*)(wih0p + 12288);          // 1048576 h
    float* bsum1 = (float*)(wih1h + 1048576);     // 2048 f
    float* hst  = bsum1 + 2048;                   // 65536 f
    float* cst  = hst + 65536;                    // 65536 f
    float* hsm  = cst + 65536;                    // 32768 f
    float* xp1  = hsm + 32768;                    // 2 * 8388608 f = 64 MB
    f16* out0h  = (f16*)(xp1 + 2 * XPS);          // 33554432 h = 64 MB

    k_prep<<<dim3(4096), dim3(256), 0, stream>>>(
        w_hh0, w_hh1, w_ih0, w_ih1, b_ih1, b_hh1,
        Wkr, Wkl, Wst, wih0p, wih1h, bsum1);

    k_rec0<<<dim3(128), dim3(256), 0, stream>>>(
        Wkr, Wkl, (const uint4*)Wst, wih0p, b_ih0, b_hh0, x, out0h, hst, cst);

    for (int j = 0; j <= NCHUNK; ++j) {
        k_pipe<<<dim3(256), dim3(256), 0, stream>>>(
            j, Wkr, Wkl, (const uint4*)Wst, out0h, wih1h, bsum1, xp1, hst, cst, hsm);
    }

    k_fc<<<dim3(64), dim3(32), 0, stream>>>(hsm, fc_w, fc_b, out);
}

// Round 6
// 12535.841 us; speedup vs baseline: 2.2398x; 1.0526x over previous
//
#include <hip/hip_runtime.h>

#define NB 64
#define NT 1024
#define DIN 12
#define NH 256
#define NG 1024
#define NCLS 17
#define TC 64
#define NCHUNK 16

typedef _Float16 f16;
typedef __attribute__((ext_vector_type(2))) _Float16 half2_t;
typedef __attribute__((ext_vector_type(8))) _Float16 f16x8;
typedef __attribute__((ext_vector_type(4))) float f32x4;
typedef unsigned int uint;

__device__ __forceinline__ float sigm(float v) { return 1.0f / (1.0f + __expf(-v)); }
__device__ __forceinline__ float tanh_(float v) {
    v = fminf(fmaxf(v, -15.0f), 15.0f);
    float e = __expf(2.0f * v);
    return (e - 1.0f) / (e + 1.0f);
}
__device__ __forceinline__ float dot2(uint w, uint h, float c) {
    return __builtin_amdgcn_fdot2(__builtin_bit_cast(half2_t, w),
                                  __builtin_bit_cast(half2_t, h), c, false);
}
__device__ __forceinline__ uint pack16(float a, float b) {
    union { f16 h[2]; uint u; } cv; cv.h[0] = (f16)a; cv.h[1] = (f16)b; return cv.u;
}
__device__ __forceinline__ uint pkrtz(float a, float b) {
    return __builtin_bit_cast(uint, __builtin_amdgcn_cvt_pkrtz(a, b));
}
__device__ __forceinline__ unsigned short hbits(f16 v) {
    union { f16 h; unsigned short u; } cv; cv.h = v; return cv.u;
}

// ---------------------------------------------------------------------------
// k_prep: pack fp16 weights. ld = layer*2+dir.
//  Wkr [ld][q][t][kp 0..87]  (VGPR part, kp fastest -> per-lane uint4 loads)
//  Wkl [ld][q][kk 0..7][t]   (LDS part, kp=88+kk, t fastest -> conflict-free)
//  Wst [ld][grp 0..7][q][t]  uint4 (streamed part, kp=96+4grp+j, coalesced)
//  wih0p [dir][q][dp 0..5][t] packed half2 of w_ih0 input pairs
//  wih1h fp16 copy of w_ih1; bsum1 = b_ih1+b_hh1
// ---------------------------------------------------------------------------
__global__ void k_prep(const float* __restrict__ w_hh0, const float* __restrict__ w_hh1,
                       const float* __restrict__ w_ih0, const float* __restrict__ w_ih1,
                       const float* __restrict__ b_ih1, const float* __restrict__ b_hh1,
                       uint* __restrict__ Wkr, uint* __restrict__ Wkl,
                       uint* __restrict__ Wst, uint* __restrict__ wih0p,
                       f16* __restrict__ wih1h, float* __restrict__ bsum1) {
    int i = blockIdx.x * 256 + threadIdx.x;
    if (i < 4 * 4 * 256 * 88) {
        int kp = i % 88; int r = i / 88;
        int t = r & 255, q = (r >> 8) & 3, ld = r >> 10;
        const float* row = (ld < 2 ? w_hh0 : w_hh1) + (size_t)(ld & 1) * NG * NH
                         + (size_t)(q * 256 + t) * NH;
        Wkr[i] = pack16(row[2 * kp], row[2 * kp + 1]);
    }
    if (i < 4 * 4 * 8 * 256) {
        int t = i & 255; int r = i >> 8;
        int kk = r & 7, q = (r >> 3) & 3, ld = r >> 5;
        const float* row = (ld < 2 ? w_hh0 : w_hh1) + (size_t)(ld & 1) * NG * NH
                         + (size_t)(q * 256 + t) * NH;
        Wkl[i] = pack16(row[2 * (88 + kk)], row[2 * (88 + kk) + 1]);
    }
    if (i < 4 * 8 * 4 * 256 * 4) {
        int j = i & 3; int u = i >> 2;
        int t = u & 255; int r = u >> 8;
        int q = r & 3, grp = (r >> 2) & 7, ld = r >> 5;
        int kp = 96 + 4 * grp + j;
        const float* row = (ld < 2 ? w_hh0 : w_hh1) + (size_t)(ld & 1) * NG * NH
                         + (size_t)(q * 256 + t) * NH;
        Wst[i] = pack16(row[2 * kp], row[2 * kp + 1]);
    }
    if (i < 2 * 4 * 6 * 256) {
        int t = i & 255; int r = i >> 8;
        int dp = r % 6, q = (r / 6) & 3, dd = r / 24;
        const float* row = w_ih0 + ((size_t)dd * NG + q * 256 + t) * DIN;
        wih0p[i] = pack16(row[2 * dp], row[2 * dp + 1]);
    }
    if (i < 2 * NG * 2 * NH) wih1h[i] = (f16)w_ih1[i];
    if (i < 2 * NG) bsum1[i] = b_ih1[i] + b_hh1[i];
}

// ---------------------------------------------------------------------------
// rec_seq<LAYER>: one block per (dir, batch), 256 threads. Lane t owns unit t
// (gate rows t, 256+t, 512+t, 768+t). Whh fp16: 352 VGPR + 32 KB LDS resident,
// 128 KB/step streamed from L2. h carried fp32, fed to fdot2 as hi+lo fp16
// split. One __syncthreads per step; no inter-block communication.
// ---------------------------------------------------------------------------
#define VG(g) { uint4 Hhv = Hh[g], Hlv = Hl[g];                                   \
    _Pragma("unroll") for (int q = 0; q < 4; ++q) { uint4 w = wr[q][g];           \
        ah[q] = dot2(w.x, Hhv.x, ah[q]); al[q] = dot2(w.x, Hlv.x, al[q]);         \
        ah[q] = dot2(w.y, Hhv.y, ah[q]); al[q] = dot2(w.y, Hlv.y, al[q]);         \
        ah[q] = dot2(w.z, Hhv.z, ah[q]); al[q] = dot2(w.z, Hlv.z, al[q]);         \
        ah[q] = dot2(w.w, Hhv.w, ah[q]); al[q] = dot2(w.w, Hlv.w, al[q]); } }

#define SG(s) { uint4 Hhv = Hh[24 + (s)], Hlv = Hl[24 + (s)];                     \
    _Pragma("unroll") for (int q = 0; q < 4; ++q) {                               \
        uint4 w = ((s) & 1) ? sb1[q] : sb0[q];                                    \
        ah[q] = dot2(w.x, Hhv.x, ah[q]); al[q] = dot2(w.x, Hlv.x, al[q]);         \
        ah[q] = dot2(w.y, Hhv.y, ah[q]); al[q] = dot2(w.y, Hlv.y, al[q]);         \
        ah[q] = dot2(w.z, Hhv.z, ah[q]); al[q] = dot2(w.z, Hlv.z, al[q]);         \
        ah[q] = dot2(w.w, Hhv.w, ah[q]); al[q] = dot2(w.w, Hlv.w, al[q]); }       \
    if ((s) + 2 < 8) { _Pragma("unroll") for (int q = 0; q < 4; ++q) {            \
        uint4 nv = WsB[(((s) + 2) * 4 + q) * 256 + tid];                          \
        if ((s) & 1) sb1[q] = nv; else sb0[q] = nv; } } }

#define LG(k2) { uint4 Hhv = Hh[22 + (k2)], Hlv = Hl[22 + (k2)];                  \
    _Pragma("unroll") for (int q = 0; q < 4; ++q) {                               \
        uint w0 = wlds[(q * 8 + (k2) * 4 + 0) * 256 + tid];                       \
        uint w1 = wlds[(q * 8 + (k2) * 4 + 1) * 256 + tid];                       \
        uint w2 = wlds[(q * 8 + (k2) * 4 + 2) * 256 + tid];                       \
        uint w3 = wlds[(q * 8 + (k2) * 4 + 3) * 256 + tid];                       \
        ah[q] = dot2(w0, Hhv.x, ah[q]); al[q] = dot2(w0, Hlv.x, al[q]);           \
        ah[q] = dot2(w1, Hhv.y, ah[q]); al[q] = dot2(w1, Hlv.y, al[q]);           \
        ah[q] = dot2(w2, Hhv.z, ah[q]); al[q] = dot2(w2, Hlv.z, al[q]);           \
        ah[q] = dot2(w3, Hhv.w, ah[q]); al[q] = dot2(w3, Hlv.w, al[q]); } }

template <int LAYER>
__device__ void rec_seq(char* smem, int rb, int chunk, int nsteps,
                        const uint* __restrict__ Wkr, const uint* __restrict__ Wkl,
                        const uint4* __restrict__ Wst, const uint* __restrict__ wih0p,
                        const float* __restrict__ b_ih0, const float* __restrict__ b_hh0,
                        const float* __restrict__ x, const float* __restrict__ xp1par,
                        f16* __restrict__ out0h,
                        float* __restrict__ hst, float* __restrict__ cst,
                        float* __restrict__ hsm) {
    uint* wlds = (uint*)smem;                                   // [4][8][256] 32 KB
    unsigned short* hs16 = (unsigned short*)(smem + 32768);     // [2][2][256] 2 KB
    uint* wihl = (uint*)(smem + 32768 + 2048);                  // [4][6][256] 24 KB

    const int tid = threadIdx.x;
    const int dir = rb >> 6;
    const int b = rb & 63;
    const int ld = LAYER * 2 + dir;

    for (int n = tid; n < 8192; n += 256) wlds[n] = Wkl[ld * 8192 + n];
    if (LAYER == 0)
        for (int n = tid; n < 6144; n += 256) wihl[n] = wih0p[dir * 6144 + n];

    uint4 wr[4][22];
    #pragma unroll
    for (int q = 0; q < 4; ++q) {
        const uint4* src = (const uint4*)(Wkr + (size_t)((ld * 4 + q) * 256 + tid) * 88);
        #pragma unroll
        for (int m = 0; m < 22; ++m) wr[q][m] = src[m];
    }

    float bias[4] = {0.f, 0.f, 0.f, 0.f};
    if (LAYER == 0) {
        #pragma unroll
        for (int q = 0; q < 4; ++q)
            bias[q] = b_ih0[dir * NG + q * 256 + tid] + b_hh0[dir * NG + q * 256 + tid];
    }

    const int sidx = (ld * NB + b) * NH + tid;
    float cv, hv, hsv = 0.f;
    if (chunk == 0) { cv = 0.f; hv = 0.f; }
    else {
        cv = cst[sidx]; hv = hst[sidx];
        if (LAYER == 1) hsv = hsm[(dir * NB + b) * NH + tid];
    }
    {
        f16 hi = (f16)hv, lo = (f16)(hv - (float)hi);
        hs16[tid] = hbits(hi); hs16[256 + tid] = hbits(lo);
    }
    const uint4* WsB = Wst + (size_t)ld * (8 * 4 * 256);
    __syncthreads();

    #pragma unroll 1
    for (int it = 0; it < nsteps; ++it) {
        const int par = it & 1;
        const uint4* Hh = (const uint4*)(hs16 + par * 512);
        const uint4* Hl = (const uint4*)(hs16 + par * 512 + 256);

        float ah[4] = {0, 0, 0, 0}, al[4] = {0, 0, 0, 0};
        uint4 sb0[4], sb1[4];
        #pragma unroll
        for (int q = 0; q < 4; ++q) sb0[q] = WsB[(0 * 4 + q) * 256 + tid];
        #pragma unroll
        for (int q = 0; q < 4; ++q) sb1[q] = WsB[(1 * 4 + q) * 256 + tid];

        float xv[12]; float xq[4];
        if (LAYER == 0) {
            const int t = dir ? (NT - 1 - it) : it;   // L0 runs full pass (chunk 0)
            const float4* xp = (const float4*)(x + ((size_t)b * NT + t) * DIN);
            float4 A = xp[0], B4 = xp[1], C4 = xp[2];
            xv[0] = A.x;  xv[1] = A.y;  xv[2] = A.z;  xv[3] = A.w;
            xv[4] = B4.x; xv[5] = B4.y; xv[6] = B4.z; xv[7] = B4.w;
            xv[8] = C4.x; xv[9] = C4.y; xv[10] = C4.z; xv[11] = C4.w;
        } else {
            const float* p = xp1par + (((size_t)dir * NB + b) * TC + it) * NG + tid;
            #pragma unroll
            for (int q = 0; q < 4; ++q) xq[q] = p[q * 256];
        }

        VG(0)  VG(1)  VG(2)  SG(0)
        VG(3)  VG(4)  VG(5)  SG(1)
        VG(6)  VG(7)  VG(8)  SG(2)
        VG(9)  VG(10) VG(11) SG(3)
        VG(12) VG(13) VG(14) SG(4)
        VG(15) VG(16) VG(17) SG(5)
        VG(18) VG(19)        SG(6)
        VG(20) VG(21)        SG(7)
        LG(0)  LG(1)

        float z[4];
        #pragma unroll
        for (int q = 0; q < 4; ++q) z[q] = ah[q] + al[q];
        if (LAYER == 0) {
            uint xph[6];
            #pragma unroll
            for (int d = 0; d < 6; ++d) xph[d] = pkrtz(xv[2 * d], xv[2 * d + 1]);
            #pragma unroll
            for (int q = 0; q < 4; ++q) {
                float a = bias[q];
                #pragma unroll
                for (int d = 0; d < 6; ++d)
                    a = dot2(wihl[(q * 6 + d) * 256 + tid], xph[d], a);
                z[q] += a;
            }
        } else {
            #pragma unroll
            for (int q = 0; q < 4; ++q) z[q] += xq[q];
        }
        cv = sigm(z[1]) * cv + sigm(z[0]) * tanh_(z[2]);
        hv = sigm(z[3]) * tanh_(cv);
        if (LAYER == 1) hsv += hv;

        f16 hi = (f16)hv, lo = (f16)(hv - (float)hi);
        unsigned short* wo = hs16 + (par ^ 1) * 512;
        wo[tid] = hbits(hi); wo[256 + tid] = hbits(lo);
        if (LAYER == 0) {
            const int t = dir ? (NT - 1 - it) : it;
            out0h[((size_t)b * NT + t) * 512 + dir * 256 + tid] = hi;
        }
        __syncthreads();
    }

    cst[sidx] = cv; hst[sidx] = hv;
    if (LAYER == 1) hsm[(dir * NB + b) * NH + tid] = hsv;
}

// ---------------------------------------------------------------------------
// proj_role: xp1[dir][b][tl][g] = out0h[b][t][0:512] . wih1h[dir][g][0:512]
//            + bsum1, via f16 MFMA 16x16x32, direct-from-global fragments
//            (wih1h is 2 MB -> L2-resident). No LDS, no barriers.
// Block pb: dirt = pb>>6; 4 waves, wave w owns m-tile mt=(pb&63)*4+w
// (16 of the 4096 rows r = b*64+tl). Wave loops 64 n-tiles x 16 k-tiles.
// Frag maps (m89/m120): A: m=lane&15,k=quad*8+j; B: n=lane&15,k=quad*8+j;
// D: col=lane&15, row=quad*4+reg.
// ---------------------------------------------------------------------------
__device__ void proj_role(int pb, int c,
                          const f16* __restrict__ out0h, const f16* __restrict__ wih1h,
                          const float* __restrict__ bsum1, float* __restrict__ xp1par) {
    const int tid = threadIdx.x;
    const int w = tid >> 6, l = tid & 63;
    const int lane16 = l & 15, quad = l >> 4;
    const int dirt = pb >> 6;
    const int mt = (pb & 63) * 4 + w;              // 0..255

    // A-frag rows: r = mt*16 + lane16 -> (b, tl)
    const int ra = mt * 16 + lane16;
    const int ab = ra >> 6, tla = ra & 63;
    const int ta = dirt ? (NT - 1 - c * TC - tla) : (c * TC + tla);
    const f16* Arow = out0h + ((size_t)ab * NT + ta) * 512 + quad * 8;

    uint4 afr[16];
    #pragma unroll
    for (int kt = 0; kt < 16; ++kt) afr[kt] = *(const uint4*)(Arow + kt * 32);

    // D rows for store: r = mt*16 + quad*4 + reg
    int ob[4], otl[4];
    #pragma unroll
    for (int reg = 0; reg < 4; ++reg) {
        int rr = mt * 16 + quad * 4 + reg;
        ob[reg] = rr >> 6; otl[reg] = rr & 63;
    }

    const f16* Bbase = wih1h + (size_t)dirt * NG * 512 + quad * 8;

    #pragma unroll 1
    for (int nt = 0; nt < 64; ++nt) {
        const int col = nt * 16 + lane16;
        const f16* Brow = Bbase + (size_t)col * 512;
        float bias = bsum1[dirt * NG + col];

        f32x4 acc = {0.f, 0.f, 0.f, 0.f};
        #pragma unroll
        for (int kt = 0; kt < 16; ++kt) {
            uint4 bv = *(const uint4*)(Brow + kt * 32);
            acc = __builtin_amdgcn_mfma_f32_16x16x32_f16(
                __builtin_bit_cast(f16x8, afr[kt]),
                __builtin_bit_cast(f16x8, bv), acc, 0, 0, 0);
        }
        #pragma unroll
        for (int reg = 0; reg < 4; ++reg) {
            xp1par[((size_t)(dirt * NB + ob[reg]) * TC + otl[reg]) * NG + col]
                = acc[reg] + bias;
        }
    }
}

// ---------------------------------------------------------------------------
// Phase A: layer 0, full 1024 steps, 128 independent blocks.
// ---------------------------------------------------------------------------
__global__ __launch_bounds__(256, 1) void k_rec0(
    const uint* __restrict__ Wkr, const uint* __restrict__ Wkl,
    const uint4* __restrict__ Wst, const uint* __restrict__ wih0p,
    const float* __restrict__ b_ih0, const float* __restrict__ b_hh0,
    const float* __restrict__ x, f16* __restrict__ out0h,
    float* __restrict__ hst, float* __restrict__ cst) {
    __shared__ __align__(16) char smem[59392];
    rec_seq<0>(smem, blockIdx.x, 0, NT, Wkr, Wkl, Wst, wih0p, b_ih0, b_hh0,
               x, nullptr, out0h, hst, cst, nullptr);
}

// ---------------------------------------------------------------------------
// Phase B launch j: blocks 0..127 = L1 chunk j-1; blocks 128..255 = proj chunk j.
// ---------------------------------------------------------------------------
#define XPS ((size_t)2 * NB * TC * NG)

__global__ __launch_bounds__(256, 1) void k_pipe(
    int j,
    const uint* __restrict__ Wkr, const uint* __restrict__ Wkl,
    const uint4* __restrict__ Wst,
    const f16* __restrict__ out0h, const f16* __restrict__ wih1h,
    const float* __restrict__ bsum1, float* __restrict__ xp1,
    float* __restrict__ hst, float* __restrict__ cst, float* __restrict__ hsm) {
    __shared__ __align__(16) char smem[59392];
    const int bid = blockIdx.x;
    if (bid < 128) {
        const int cc = j - 1;
        if (cc >= 0 && cc < NCHUNK)
            rec_seq<1>(smem, bid, cc, TC, Wkr, Wkl, Wst, nullptr, nullptr, nullptr,
                       nullptr, xp1 + (size_t)(cc & 1) * XPS, nullptr, hst, cst, hsm);
    } else {
        const int cp = j;
        if (cp < NCHUNK)
            proj_role(bid - 128, cp, out0h, wih1h, bsum1,
                      xp1 + (size_t)(cp & 1) * XPS);
    }
}

// ---------------------------------------------------------------------------
__global__ void k_fc(const float* __restrict__ hsm, const float* __restrict__ fc_w,
                     const float* __restrict__ fc_b, float* __restrict__ out) {
    const int b = blockIdx.x;
    const int n = threadIdx.x;
    if (n >= NCLS) return;
    float acc = fc_b[n];
    const float inv = 1.0f / (float)NT;
    for (int k = 0; k < 2 * NH; ++k) {
        float pv = hsm[((k >> 8) * NB + b) * NH + (k & 255)];
        acc += (pv * inv) * fc_w[n * 2 * NH + k];
    }
    out[b * NCLS + n] = acc;
}

// ---------------------------------------------------------------------------
extern "C" void kernel_launch(void* const* d_in, const int* in_sizes, int n_in,
                              void* d_out, int out_size, void* d_ws, size_t ws_size,
                              hipStream_t stream) {
    const float* x     = (const float*)d_in[0];
    const float* w_ih0 = (const float*)d_in[1];
    const float* w_hh0 = (const float*)d_in[2];
    const float* b_ih0 = (const float*)d_in[3];
    const float* b_hh0 = (const float*)d_in[4];
    const float* w_ih1 = (const float*)d_in[5];
    const float* w_hh1 = (const float*)d_in[6];
    const float* b_ih1 = (const float*)d_in[7];
    const float* b_hh1 = (const float*)d_in[8];
    const float* fc_w  = (const float*)d_in[9];
    const float* fc_b  = (const float*)d_in[10];
    float* out = (float*)d_out;

    char* ws = (char*)d_ws;
    uint* Wkr   = (uint*)ws;                      // 360448 u
    uint* Wkl   = Wkr + 360448;                   // 32768 u
    uint* Wst   = Wkl + 32768;                    // 131072 u
    uint* wih0p = Wst + 131072;                   // 12288 u
    f16* wih1h  = (f16*)(wih0p + 12288);          // 1048576 h
    float* bsum1 = (float*)(wih1h + 1048576);     // 2048 f
    float* hst  = bsum1 + 2048;                   // 65536 f
    float* cst  = hst + 65536;                    // 65536 f
    float* hsm  = cst + 65536;                    // 32768 f
    float* xp1  = hsm + 32768;                    // 2 * 8388608 f = 64 MB
    f16* out0h  = (f16*)(xp1 + 2 * XPS);          // 33554432 h = 64 MB

    k_prep<<<dim3(4096), dim3(256), 0, stream>>>(
        w_hh0, w_hh1, w_ih0, w_ih1, b_ih1, b_hh1,
        Wkr, Wkl, Wst, wih0p, wih1h, bsum1);

    k_rec0<<<dim3(128), dim3(256), 0, stream>>>(
        Wkr, Wkl, (const uint4*)Wst, wih0p, b_ih0, b_hh0, x, out0h, hst, cst);

    for (int j = 0; j <= NCHUNK; ++j) {
        k_pipe<<<dim3(256), dim3(256), 0, stream>>>(
            j, Wkr, Wkl, (const uint4*)Wst, out0h, wih1h, bsum1, xp1, hst, cst, hsm);
    }

    k_fc<<<dim3(64), dim3(32), 0, stream>>>(hsm, fc_w, fc_b, out);
}

// Round 7
// 7720.110 us; speedup vs baseline: 3.6370x; 1.6238x over previous
//
#include <hip/hip_runtime.h>

#define NB 64
#define NT 1024
#define DIN 12
#define NH 256
#define NG 1024
#define NCLS 17
#define TCL 256
#define NCHUNK 4

typedef _Float16 f16;
typedef __attribute__((ext_vector_type(2))) _Float16 half2_t;
typedef __attribute__((ext_vector_type(8))) _Float16 f16x8;
typedef __attribute__((ext_vector_type(4))) float f32x4;
typedef unsigned int uint;

__device__ __forceinline__ float sigm(float v) { return 1.0f / (1.0f + __expf(-v)); }
__device__ __forceinline__ float tanh_(float v) {
    v = fminf(fmaxf(v, -15.0f), 15.0f);
    float e = __expf(2.0f * v);
    return (e - 1.0f) / (e + 1.0f);
}
__device__ __forceinline__ float dot2(uint w, uint h, float c) {
    return __builtin_amdgcn_fdot2(__builtin_bit_cast(half2_t, w),
                                  __builtin_bit_cast(half2_t, h), c, false);
}
__device__ __forceinline__ uint pack16(float a, float b) {
    union { f16 h[2]; uint u; } cv; cv.h[0] = (f16)a; cv.h[1] = (f16)b; return cv.u;
}
__device__ __forceinline__ uint pkrtz(float a, float b) {
    return __builtin_bit_cast(uint, __builtin_amdgcn_cvt_pkrtz(a, b));
}
__device__ __forceinline__ unsigned short hbits(f16 v) {
    union { f16 h; unsigned short u; } cv; cv.h = v; return cv.u;
}

// ---------------------------------------------------------------------------
// k_prep: pack fp16 weights. ld = layer*2+dir. Whh split per lane (t = unit):
//  Wkv [ld][q][t][kp 0..39]    per-lane contiguous (VGPR cache)
//  Wka [ld][q][t][kp 40..95]   per-lane contiguous (AGPR cache, 56 kp)
//  Wkl [ld][q][g4 0..7][t][j4] (LDS cache, kp = 96+4*g4+j, uint4 per (q,g4,t))
//  wih0p [dir][q][dp 0..5][t]  packed half2 of w_ih0 input pairs
//  wih1h fp16 copy of w_ih1; bsum1 = b_ih1 + b_hh1
// ---------------------------------------------------------------------------
__global__ void k_prep(const float* __restrict__ w_hh0, const float* __restrict__ w_hh1,
                       const float* __restrict__ w_ih0, const float* __restrict__ w_ih1,
                       const float* __restrict__ b_ih1, const float* __restrict__ b_hh1,
                       uint* __restrict__ Wkv, uint* __restrict__ Wka,
                       uint* __restrict__ Wkl, uint* __restrict__ wih0p,
                       f16* __restrict__ wih1h, float* __restrict__ bsum1) {
    int i = blockIdx.x * 256 + threadIdx.x;
    if (i < 4 * 4 * 256 * 40) {            // Wkv: 163840
        int kp = i % 40; int r = i / 40;
        int t = r & 255, q = (r >> 8) & 3, ld = r >> 10;
        const float* row = (ld < 2 ? w_hh0 : w_hh1) + (size_t)(ld & 1) * NG * NH
                         + (size_t)(q * 256 + t) * NH;
        Wkv[i] = pack16(row[2 * kp], row[2 * kp + 1]);
    }
    if (i < 4 * 4 * 256 * 56) {            // Wka: 229376
        int kp = 40 + (i % 56); int r = i / 56;
        int t = r & 255, q = (r >> 8) & 3, ld = r >> 10;
        const float* row = (ld < 2 ? w_hh0 : w_hh1) + (size_t)(ld & 1) * NG * NH
                         + (size_t)(q * 256 + t) * NH;
        Wka[i] = pack16(row[2 * kp], row[2 * kp + 1]);
    }
    if (i < 4 * 4 * 8 * 256 * 4) {         // Wkl: 131072
        int j = i & 3; int u = i >> 2;
        int t = u & 255, g4 = (u >> 8) & 7, q = (u >> 11) & 3, ld = u >> 13;
        int kp = 96 + 4 * g4 + j;
        const float* row = (ld < 2 ? w_hh0 : w_hh1) + (size_t)(ld & 1) * NG * NH
                         + (size_t)(q * 256 + t) * NH;
        Wkl[i] = pack16(row[2 * kp], row[2 * kp + 1]);
    }
    if (i < 2 * 4 * 6 * 256) {             // wih0p: 12288
        int t = i & 255; int r = i >> 8;
        int dp = r % 6, q = (r / 6) & 3, dd = r / 24;
        const float* row = w_ih0 + ((size_t)dd * NG + q * 256 + t) * DIN;
        wih0p[i] = pack16(row[2 * dp], row[2 * dp + 1]);
    }
    if (i < 2 * NG * 2 * NH) wih1h[i] = (f16)w_ih1[i];
    if (i < 2 * NG) bsum1[i] = b_ih1[i] + b_hh1[i];
}

// ---------------------------------------------------------------------------
// rec_seq<LAYER>: one block per (dir, batch), 256 threads. Lane t owns unit t
// (gate rows t, 256+t, 512+t, 768+t). Whh fp16 fully CU-resident:
// 160 VGPR uints + 224 AGPR uints (explicit accvgpr asm) + 128 KB LDS.
// h carried fp32, fed to fdot2 as hi+lo fp16 split. One barrier per step.
// ---------------------------------------------------------------------------
template <int LAYER>
__device__ void rec_seq(char* smem, int rb, int chunk, int nsteps,
                        const uint* __restrict__ Wkv, const uint* __restrict__ Wka,
                        const uint* __restrict__ Wkl, const uint* __restrict__ wih0p,
                        const float* __restrict__ b_ih0, const float* __restrict__ b_hh0,
                        const float* __restrict__ x, const float* __restrict__ xp1,
                        f16* __restrict__ out0h,
                        float* __restrict__ hst, float* __restrict__ cst,
                        float* __restrict__ hsm) {
    uint4* wlds4 = (uint4*)smem;                               // [4][8][256] uint4 = 128 KB
    unsigned short* hs16 = (unsigned short*)(smem + 131072);   // [2 par][2 hi/lo][256] 2 KB
    uint* wihl = (uint*)(smem + 133120);                       // [4][6][256] 24 KB (L0)

    const int tid = threadIdx.x;
    const int dir = rb >> 6;
    const int b = rb & 63;
    const int ld = LAYER * 2 + dir;

    // LDS weight slice (kp 96..127)
    for (int n = tid; n < 8192; n += 256) wlds4[n] = ((const uint4*)Wkl)[ld * 8192 + n];
    if (LAYER == 0)
        for (int n = tid; n < 6144; n += 256) wihl[n] = wih0p[dir * 6144 + n];

    // VGPR weight cache (kp 0..39)
    uint4 wrv[4][10];
    #pragma unroll
    for (int q = 0; q < 4; ++q) {
        const uint* src = Wkv + (size_t)((ld * 4 + q) * 256 + tid) * 40;
        #pragma unroll
        for (int m = 0; m < 10; ++m) wrv[q][m] = *(const uint4*)(src + m * 4);
    }

    // AGPR weight cache (kp 40..95): 224 uints per lane in AGPRs
    uint aw[224];
    #pragma unroll
    for (int q = 0; q < 4; ++q) {
        const uint* src = Wka + (size_t)((ld * 4 + q) * 256 + tid) * 56;
        #pragma unroll
        for (int m = 0; m < 14; ++m) {
            uint4 v = *(const uint4*)(src + m * 4);
            asm volatile("v_accvgpr_write_b32 %0, %1" : "=a"(aw[(q * 14 + m) * 4 + 0]) : "v"(v.x));
            asm volatile("v_accvgpr_write_b32 %0, %1" : "=a"(aw[(q * 14 + m) * 4 + 1]) : "v"(v.y));
            asm volatile("v_accvgpr_write_b32 %0, %1" : "=a"(aw[(q * 14 + m) * 4 + 2]) : "v"(v.z));
            asm volatile("v_accvgpr_write_b32 %0, %1" : "=a"(aw[(q * 14 + m) * 4 + 3]) : "v"(v.w));
        }
    }

    float bias[4] = {0.f, 0.f, 0.f, 0.f};
    if (LAYER == 0) {
        #pragma unroll
        for (int q = 0; q < 4; ++q)
            bias[q] = b_ih0[dir * NG + q * 256 + tid] + b_hh0[dir * NG + q * 256 + tid];
    }

    const int sidx = (ld * NB + b) * NH + tid;
    float cv, hv, hsv = 0.f;
    if (chunk == 0) { cv = 0.f; hv = 0.f; }
    else {
        cv = cst[sidx]; hv = hst[sidx];
        if (LAYER == 1) hsv = hsm[(dir * NB + b) * NH + tid];
    }
    {
        f16 hi = (f16)hv, lo = (f16)(hv - (float)hi);
        hs16[tid] = hbits(hi); hs16[256 + tid] = hbits(lo);
    }
    __syncthreads();

    #pragma unroll 1
    for (int it = 0; it < nsteps; ++it) {
        const int par = it & 1;
        const uint4* Hh = (const uint4*)(hs16 + par * 512);
        const uint4* Hl = (const uint4*)(hs16 + par * 512 + 256);

        float ah[4] = {0, 0, 0, 0}, al[4] = {0, 0, 0, 0};

        float xv[12]; float xq[4];
        if (LAYER == 0) {
            const int t = dir ? (NT - 1 - it) : it;
            const float4* xp = (const float4*)(x + ((size_t)b * NT + t) * DIN);
            float4 A = xp[0], B4 = xp[1], C4 = xp[2];
            xv[0] = A.x;  xv[1] = A.y;  xv[2] = A.z;  xv[3] = A.w;
            xv[4] = B4.x; xv[5] = B4.y; xv[6] = B4.z; xv[7] = B4.w;
            xv[8] = C4.x; xv[9] = C4.y; xv[10] = C4.z; xv[11] = C4.w;
        } else {
            const int s = chunk * TCL + it;
            const float* p = xp1 + (((size_t)dir * NB + b) * TCL + it) * NG + tid;
            (void)s;
            #pragma unroll
            for (int q = 0; q < 4; ++q) xq[q] = p[q * 256];
        }

        // ---- VGPR region: kp 0..39 (g8 0..9) ----
        #pragma unroll
        for (int g8 = 0; g8 < 10; ++g8) {
            uint4 Hhv = Hh[g8], Hlv = Hl[g8];
            #pragma unroll
            for (int q = 0; q < 4; ++q) {
                uint4 w = wrv[q][g8];
                ah[q] = dot2(w.x, Hhv.x, ah[q]); al[q] = dot2(w.x, Hlv.x, al[q]);
                ah[q] = dot2(w.y, Hhv.y, ah[q]); al[q] = dot2(w.y, Hlv.y, al[q]);
                ah[q] = dot2(w.z, Hhv.z, ah[q]); al[q] = dot2(w.z, Hlv.z, al[q]);
                ah[q] = dot2(w.w, Hhv.w, ah[q]); al[q] = dot2(w.w, Hlv.w, al[q]);
            }
        }
        // ---- AGPR region: kp 40..95 (g8 10..23) ----
        #pragma unroll
        for (int m = 0; m < 14; ++m) {
            const int g8 = 10 + m;
            uint4 Hhv = Hh[g8], Hlv = Hl[g8];
            #pragma unroll
            for (int q = 0; q < 4; ++q) {
                uint w0, w1, w2, w3;
                asm volatile("v_accvgpr_read_b32 %0, %1" : "=v"(w0) : "a"(aw[(q * 14 + m) * 4 + 0]));
                asm volatile("v_accvgpr_read_b32 %0, %1" : "=v"(w1) : "a"(aw[(q * 14 + m) * 4 + 1]));
                asm volatile("v_accvgpr_read_b32 %0, %1" : "=v"(w2) : "a"(aw[(q * 14 + m) * 4 + 2]));
                asm volatile("v_accvgpr_read_b32 %0, %1" : "=v"(w3) : "a"(aw[(q * 14 + m) * 4 + 3]));
                ah[q] = dot2(w0, Hhv.x, ah[q]); al[q] = dot2(w0, Hlv.x, al[q]);
                ah[q] = dot2(w1, Hhv.y, ah[q]); al[q] = dot2(w1, Hlv.y, al[q]);
                ah[q] = dot2(w2, Hhv.z, ah[q]); al[q] = dot2(w2, Hlv.z, al[q]);
                ah[q] = dot2(w3, Hhv.w, ah[q]); al[q] = dot2(w3, Hlv.w, al[q]);
            }
        }
        // ---- LDS region: kp 96..127 (g8 24..31) ----
        #pragma unroll
        for (int g4 = 0; g4 < 8; ++g4) {
            const int g8 = 24 + g4;
            uint4 Hhv = Hh[g8], Hlv = Hl[g8];
            #pragma unroll
            for (int q = 0; q < 4; ++q) {
                uint4 w = wlds4[(q * 8 + g4) * 256 + tid];
                ah[q] = dot2(w.x, Hhv.x, ah[q]); al[q] = dot2(w.x, Hlv.x, al[q]);
                ah[q] = dot2(w.y, Hhv.y, ah[q]); al[q] = dot2(w.y, Hlv.y, al[q]);
                ah[q] = dot2(w.z, Hhv.z, ah[q]); al[q] = dot2(w.z, Hlv.z, al[q]);
                ah[q] = dot2(w.w, Hhv.w, ah[q]); al[q] = dot2(w.w, Hlv.w, al[q]);
            }
        }

        // ---- activation ----
        float z[4];
        #pragma unroll
        for (int q = 0; q < 4; ++q) z[q] = ah[q] + al[q];
        if (LAYER == 0) {
            uint xph[6];
            #pragma unroll
            for (int d = 0; d < 6; ++d) xph[d] = pkrtz(xv[2 * d], xv[2 * d + 1]);
            #pragma unroll
            for (int q = 0; q < 4; ++q) {
                float a = bias[q];
                #pragma unroll
                for (int d = 0; d < 6; ++d)
                    a = dot2(wihl[(q * 6 + d) * 256 + tid], xph[d], a);
                z[q] += a;
            }
        } else {
            #pragma unroll
            for (int q = 0; q < 4; ++q) z[q] += xq[q];
        }
        cv = sigm(z[1]) * cv + sigm(z[0]) * tanh_(z[2]);
        hv = sigm(z[3]) * tanh_(cv);
        if (LAYER == 1) hsv += hv;

        f16 hi = (f16)hv, lo = (f16)(hv - (float)hi);
        unsigned short* wo = hs16 + (par ^ 1) * 512;
        wo[tid] = hbits(hi); wo[256 + tid] = hbits(lo);
        if (LAYER == 0) {
            const int t = dir ? (NT - 1 - it) : it;
            out0h[((size_t)b * NT + t) * 512 + dir * 256 + tid] = hi;
        }
        __syncthreads();
    }

    cst[sidx] = cv; hst[sidx] = hv;
    if (LAYER == 1) hsm[(dir * NB + b) * NH + tid] = hsv;
}

// ---------------------------------------------------------------------------
// k_proj (chunk c): xp1[dir][b][tl][g] = out0h[b][t][0:512].wih1h[dir][g][0:512]
// + bsum1, f16 MFMA 16x16x32 direct-from-global (verified layout, round 6).
// Grid 512 blocks x 4 waves; wave owns one 16-row m-tile of the 16384 rows.
// ---------------------------------------------------------------------------
__global__ __launch_bounds__(256, 2) void k_proj(
    int c, const f16* __restrict__ out0h, const f16* __restrict__ wih1h,
    const float* __restrict__ bsum1, float* __restrict__ xp1) {
    const int tid = threadIdx.x;
    const int w = tid >> 6, l = tid & 63;
    const int lane16 = l & 15, quad = l >> 4;
    const int pb = blockIdx.x;
    const int dirt = pb >> 8;
    const int mt = (pb & 255) * 4 + w;             // 0..1023

    const int ra = mt * 16 + lane16;               // row over b(64) x tl(256)
    const int ab = ra >> 8, tla = ra & 255;
    const int ta = dirt ? (NT - 1 - c * TCL - tla) : (c * TCL + tla);
    const f16* Arow = out0h + ((size_t)ab * NT + ta) * 512 + quad * 8;

    uint4 afr[16];
    #pragma unroll
    for (int kt = 0; kt < 16; ++kt) afr[kt] = *(const uint4*)(Arow + kt * 32);

    int ob[4], otl[4];
    #pragma unroll
    for (int reg = 0; reg < 4; ++reg) {
        int rr = mt * 16 + quad * 4 + reg;
        ob[reg] = rr >> 8; otl[reg] = rr & 255;
    }

    const f16* Bbase = wih1h + (size_t)dirt * NG * 512 + quad * 8;

    #pragma unroll 1
    for (int nt = 0; nt < 64; ++nt) {
        const int col = nt * 16 + lane16;
        const f16* Brow = Bbase + (size_t)col * 512;
        float bias = bsum1[dirt * NG + col];

        f32x4 acc = {0.f, 0.f, 0.f, 0.f};
        #pragma unroll
        for (int kt = 0; kt < 16; ++kt) {
            uint4 bv = *(const uint4*)(Brow + kt * 32);
            acc = __builtin_amdgcn_mfma_f32_16x16x32_f16(
                __builtin_bit_cast(f16x8, afr[kt]),
                __builtin_bit_cast(f16x8, bv), acc, 0, 0, 0);
        }
        #pragma unroll
        for (int reg = 0; reg < 4; ++reg) {
            xp1[((size_t)(dirt * NB + ob[reg]) * TCL + otl[reg]) * NG + col]
                = acc[reg] + bias;
        }
    }
}

// ---------------------------------------------------------------------------
__global__ __launch_bounds__(256, 1) void k_rec0(
    const uint* __restrict__ Wkv, const uint* __restrict__ Wka,
    const uint* __restrict__ Wkl, const uint* __restrict__ wih0p,
    const float* __restrict__ b_ih0, const float* __restrict__ b_hh0,
    const float* __restrict__ x, f16* __restrict__ out0h,
    float* __restrict__ hst, float* __restrict__ cst) {
    extern __shared__ __align__(16) char smem[];
    rec_seq<0>(smem, blockIdx.x, 0, NT, Wkv, Wka, Wkl, wih0p, b_ih0, b_hh0,
               x, nullptr, out0h, hst, cst, nullptr);
}

__global__ __launch_bounds__(256, 1) void k_rec1(
    int c,
    const uint* __restrict__ Wkv, const uint* __restrict__ Wka,
    const uint* __restrict__ Wkl, const float* __restrict__ xp1,
    float* __restrict__ hst, float* __restrict__ cst, float* __restrict__ hsm) {
    extern __shared__ __align__(16) char smem[];
    rec_seq<1>(smem, blockIdx.x, c, TCL, Wkv, Wka, Wkl, nullptr, nullptr, nullptr,
               nullptr, xp1, nullptr, hst, cst, hsm);
}

// ---------------------------------------------------------------------------
__global__ void k_fc(const float* __restrict__ hsm, const float* __restrict__ fc_w,
                     const float* __restrict__ fc_b, float* __restrict__ out) {
    const int b = blockIdx.x;
    const int n = threadIdx.x;
    if (n >= NCLS) return;
    float acc = fc_b[n];
    const float inv = 1.0f / (float)NT;
    for (int k = 0; k < 2 * NH; ++k) {
        float pv = hsm[((k >> 8) * NB + b) * NH + (k & 255)];
        acc += (pv * inv) * fc_w[n * 2 * NH + k];
    }
    out[b * NCLS + n] = acc;
}

// ---------------------------------------------------------------------------
extern "C" void kernel_launch(void* const* d_in, const int* in_sizes, int n_in,
                              void* d_out, int out_size, void* d_ws, size_t ws_size,
                              hipStream_t stream) {
    const float* x     = (const float*)d_in[0];
    const float* w_ih0 = (const float*)d_in[1];
    const float* w_hh0 = (const float*)d_in[2];
    const float* b_ih0 = (const float*)d_in[3];
    const float* b_hh0 = (const float*)d_in[4];
    const float* w_ih1 = (const float*)d_in[5];
    const float* w_hh1 = (const float*)d_in[6];
    const float* b_ih1 = (const float*)d_in[7];
    const float* b_hh1 = (const float*)d_in[8];
    const float* fc_w  = (const float*)d_in[9];
    const float* fc_b  = (const float*)d_in[10];
    float* out = (float*)d_out;

    char* ws = (char*)d_ws;
    uint* Wkv   = (uint*)ws;                      // 163840 u
    uint* Wka   = Wkv + 163840;                   // 229376 u
    uint* Wkl   = Wka + 229376;                   // 131072 u
    uint* wih0p = Wkl + 131072;                   // 12288 u
    f16* wih1h  = (f16*)(wih0p + 12288);          // 1048576 h
    float* bsum1 = (float*)(wih1h + 1048576);     // 2048 f
    float* hst  = bsum1 + 2048;                   // 65536 f
    float* cst  = hst + 65536;                    // 65536 f
    float* hsm  = cst + 65536;                    // 32768 f
    float* xp1  = hsm + 32768;                    // 2*64*256*1024 f = 128 MB
    f16* out0h  = (f16*)(xp1 + (size_t)2 * NB * TCL * NG);   // 64 MB

    k_prep<<<dim3(4096), dim3(256), 0, stream>>>(
        w_hh0, w_hh1, w_ih0, w_ih1, b_ih1, b_hh1,
        Wkv, Wka, Wkl, wih0p, wih1h, bsum1);

    k_rec0<<<dim3(128), dim3(256), 157696, stream>>>(
        Wkv, Wka, Wkl, wih0p, b_ih0, b_hh0, x, out0h, hst, cst);

    for (int c = 0; c < NCHUNK; ++c) {
        k_proj<<<dim3(512), dim3(256), 0, stream>>>(c, out0h, wih1h, bsum1, xp1);
        k_rec1<<<dim3(128), dim3(256), 133120, stream>>>(
            c, Wkv, Wka, Wkl, xp1, hst, cst, hsm);
    }

    k_fc<<<dim3(64), dim3(32), 0, stream>>>(hsm, fc_w, fc_b, out);
}

// Round 8
// 4978.172 us; speedup vs baseline: 5.6402x; 1.5508x over previous
//
#include <hip/hip_runtime.h>

#define NB 64
#define NT 1024
#define DIN 12
#define NH 256
#define NG 1024
#define NCLS 17
#define TCL 128
#define NCHUNK 8
#define XPS ((size_t)2 * NB * TCL * NG)   // floats per xp1 chunk buffer

typedef _Float16 f16;
typedef __attribute__((ext_vector_type(2))) _Float16 half2_t;
typedef __attribute__((ext_vector_type(8))) _Float16 f16x8;
typedef __attribute__((ext_vector_type(4))) float f32x4;
typedef unsigned int uint;
typedef unsigned short ushort;

__device__ __forceinline__ float sigm(float v) { return 1.0f / (1.0f + __expf(-v)); }
__device__ __forceinline__ float tanh_(float v) {
    v = fminf(fmaxf(v, -15.0f), 15.0f);
    float e = __expf(2.0f * v);
    return (e - 1.0f) / (e + 1.0f);
}
__device__ __forceinline__ float dot2(uint w, uint h, float c) {
    return __builtin_amdgcn_fdot2(__builtin_bit_cast(half2_t, w),
                                  __builtin_bit_cast(half2_t, h), c, false);
}
__device__ __forceinline__ uint pack16(float a, float b) {
    union { f16 h[2]; uint u; } cv; cv.h[0] = (f16)a; cv.h[1] = (f16)b; return cv.u;
}
__device__ __forceinline__ uint pkrtz(float a, float b) {
    return __builtin_bit_cast(uint, __builtin_amdgcn_cvt_pkrtz(a, b));
}
__device__ __forceinline__ ushort hbits(f16 v) {
    union { f16 h; ushort u; } cv; cv.h = v; return cv.u;
}

// ---------------------------------------------------------------------------
// k_prep: pack fp16 weights. ld = layer*2+dir. Whh kp index = k/2 (0..127):
//  Wkv [ld][q][t][kp 0..39]    per-lane contiguous  (VGPR cache, 160 uints)
//  Wka [ld][q][t][kp 40..99]   per-lane contiguous  (AGPR cache, 240 uints)
//  Wkl [ld][q][g 0..6][t]      uint4 (LDS cache, kp = 100+4g+j, 112 KB)
//  wih0p [dir][q][dp 0..5][t]  packed half2 of w_ih0 input pairs
//  wih1h fp16 copy of w_ih1; bsum1 = b_ih1 + b_hh1
// ---------------------------------------------------------------------------
__global__ void k_prep(const float* __restrict__ w_hh0, const float* __restrict__ w_hh1,
                       const float* __restrict__ w_ih0, const float* __restrict__ w_ih1,
                       const float* __restrict__ b_ih1, const float* __restrict__ b_hh1,
                       uint* __restrict__ Wkv, uint* __restrict__ Wka,
                       uint* __restrict__ Wkl, uint* __restrict__ wih0p,
                       f16* __restrict__ wih1h, float* __restrict__ bsum1) {
    int i = blockIdx.x * 256 + threadIdx.x;
    if (i < 4 * 4 * 256 * 40) {            // Wkv: 163840 uints
        int kp = i % 40; int r = i / 40;
        int t = r & 255, q = (r >> 8) & 3, ld = r >> 10;
        const float* row = (ld < 2 ? w_hh0 : w_hh1) + (size_t)(ld & 1) * NG * NH
                         + (size_t)(q * 256 + t) * NH;
        Wkv[i] = pack16(row[2 * kp], row[2 * kp + 1]);
    }
    if (i < 4 * 4 * 256 * 60) {            // Wka: 245760 uints
        int kp = 40 + (i % 60); int r = i / 60;
        int t = r & 255, q = (r >> 8) & 3, ld = r >> 10;
        const float* row = (ld < 2 ? w_hh0 : w_hh1) + (size_t)(ld & 1) * NG * NH
                         + (size_t)(q * 256 + t) * NH;
        Wka[i] = pack16(row[2 * kp], row[2 * kp + 1]);
    }
    if (i < 4 * 4 * 7 * 256 * 4) {         // Wkl: 114688 uints
        int j = i & 3; int u = i >> 2;
        int t = u & 255; int v = u >> 8;
        int g = v % 7; int w2 = v / 7;
        int q = w2 & 3, ld = w2 >> 2;
        int kp = 100 + 4 * g + j;
        const float* row = (ld < 2 ? w_hh0 : w_hh1) + (size_t)(ld & 1) * NG * NH
                         + (size_t)(q * 256 + t) * NH;
        Wkl[i] = pack16(row[2 * kp], row[2 * kp + 1]);
    }
    if (i < 2 * 4 * 6 * 256) {             // wih0p: 12288 uints
        int t = i & 255; int r = i >> 8;
        int dp = r % 6, q = (r / 6) & 3, dd = r / 24;
        const float* row = w_ih0 + ((size_t)dd * NG + q * 256 + t) * DIN;
        wih0p[i] = pack16(row[2 * dp], row[2 * dp + 1]);
    }
    if (i < 2 * NG * 2 * NH) wih1h[i] = (f16)w_ih1[i];
    if (i < 2 * NG) bsum1[i] = b_ih1[i] + b_hh1[i];
}

// ---------------------------------------------------------------------------
// rec_seq<LAYER>: one block per (dir, batch), 256 threads. Lane t owns unit t
// (gate rows t, 256+t, 512+t, 768+t). Whh fp16 fully CU-resident:
// 160 VGPR + 240 AGPR uints per lane + 112 KB LDS. h carried fp32 across
// steps but broadcast as single fp16 (hi) — the only recurrent-path noise is
// ~2^-12 h rounding, ~5x below the static fp16 weight rounding (round-5
// measured 2.4e-4 with hi/lo). One barrier per step; no inter-block comms.
// ---------------------------------------------------------------------------
template <int LAYER>
__device__ void rec_seq(char* smem, int rb, int chunk, int nsteps,
                        const uint* __restrict__ Wkv, const uint* __restrict__ Wka,
                        const uint* __restrict__ Wkl, const uint* __restrict__ wih0p,
                        const float* __restrict__ b_ih0, const float* __restrict__ b_hh0,
                        const float* __restrict__ x, const float* __restrict__ xp1,
                        f16* __restrict__ out0h,
                        float* __restrict__ hst, float* __restrict__ cst,
                        float* __restrict__ hsm) {
    uint4* wlds4 = (uint4*)smem;                         // [4][7][256] uint4 = 112 KB
    ushort* hs16 = (ushort*)(smem + 114688);             // [2 par][256] f16 = 1 KB
    uint* wihl = (uint*)(smem + 115712);                 // [4][6][256] = 24 KB (L0 only)

    const int tid = threadIdx.x;
    const int dir = rb >> 6;
    const int b = rb & 63;
    const int ld = LAYER * 2 + dir;

    // LDS weight slice (kp 100..127)
    for (int n = tid; n < 7168; n += 256) wlds4[n] = ((const uint4*)Wkl)[ld * 7168 + n];
    if (LAYER == 0)
        for (int n = tid; n < 6144; n += 256) wihl[n] = wih0p[dir * 6144 + n];

    // VGPR weight cache (kp 0..39)
    uint4 wrv[4][10];
    #pragma unroll
    for (int q = 0; q < 4; ++q) {
        const uint* src = Wkv + (size_t)((ld * 4 + q) * 256 + tid) * 40;
        #pragma unroll
        for (int m = 0; m < 10; ++m) wrv[q][m] = *(const uint4*)(src + m * 4);
    }

    // AGPR weight cache (kp 40..99): 240 uints per lane
    uint aw[240];
    #pragma unroll
    for (int q = 0; q < 4; ++q) {
        const uint* src = Wka + (size_t)((ld * 4 + q) * 256 + tid) * 60;
        #pragma unroll
        for (int m = 0; m < 15; ++m) {
            uint4 v = *(const uint4*)(src + m * 4);
            asm volatile("v_accvgpr_write_b32 %0, %1" : "=a"(aw[(q * 15 + m) * 4 + 0]) : "v"(v.x));
            asm volatile("v_accvgpr_write_b32 %0, %1" : "=a"(aw[(q * 15 + m) * 4 + 1]) : "v"(v.y));
            asm volatile("v_accvgpr_write_b32 %0, %1" : "=a"(aw[(q * 15 + m) * 4 + 2]) : "v"(v.z));
            asm volatile("v_accvgpr_write_b32 %0, %1" : "=a"(aw[(q * 15 + m) * 4 + 3]) : "v"(v.w));
        }
    }

    float bias[4] = {0.f, 0.f, 0.f, 0.f};
    if (LAYER == 0) {
        #pragma unroll
        for (int q = 0; q < 4; ++q)
            bias[q] = b_ih0[dir * NG + q * 256 + tid] + b_hh0[dir * NG + q * 256 + tid];
    }

    const int sidx = (ld * NB + b) * NH + tid;
    float cv, hv, hsv = 0.f;
    if (chunk == 0) { cv = 0.f; hv = 0.f; }
    else {
        cv = cst[sidx]; hv = hst[sidx];
        if (LAYER == 1) hsv = hsm[(dir * NB + b) * NH + tid];
    }
    hs16[tid] = hbits((f16)hv);
    __syncthreads();

    #pragma unroll 1
    for (int it = 0; it < nsteps; ++it) {
        const int par = it & 1;
        const uint4* Hh = (const uint4*)(hs16 + par * 256);

        float ah[4] = {0, 0, 0, 0};

        float xv[12]; float4 xq4;
        if (LAYER == 0) {
            const int t = dir ? (NT - 1 - it) : it;
            const float4* xp = (const float4*)(x + ((size_t)b * NT + t) * DIN);
            float4 A = xp[0], B4 = xp[1], C4 = xp[2];
            xv[0] = A.x;  xv[1] = A.y;  xv[2] = A.z;  xv[3] = A.w;
            xv[4] = B4.x; xv[5] = B4.y; xv[6] = B4.z; xv[7] = B4.w;
            xv[8] = C4.x; xv[9] = C4.y; xv[10] = C4.z; xv[11] = C4.w;
        } else {
            xq4 = *(const float4*)(xp1 + (((size_t)dir * NB + b) * TCL + it) * NG + tid * 4);
        }

        // ---- VGPR region: kp 0..39 (g8 0..9) ----
        #pragma unroll
        for (int g8 = 0; g8 < 10; ++g8) {
            uint4 Hhv = Hh[g8];
            #pragma unroll
            for (int q = 0; q < 4; ++q) {
                uint4 w = wrv[q][g8];
                ah[q] = dot2(w.x, Hhv.x, ah[q]);
                ah[q] = dot2(w.y, Hhv.y, ah[q]);
                ah[q] = dot2(w.z, Hhv.z, ah[q]);
                ah[q] = dot2(w.w, Hhv.w, ah[q]);
            }
        }
        // ---- AGPR region: kp 40..99 (g8 10..24) ----
        #pragma unroll
        for (int m = 0; m < 15; ++m) {
            const int g8 = 10 + m;
            uint4 Hhv = Hh[g8];
            #pragma unroll
            for (int q = 0; q < 4; ++q) {
                uint w0, w1, w2, w3;
                asm volatile("v_accvgpr_read_b32 %0, %1" : "=v"(w0) : "a"(aw[(q * 15 + m) * 4 + 0]));
                asm volatile("v_accvgpr_read_b32 %0, %1" : "=v"(w1) : "a"(aw[(q * 15 + m) * 4 + 1]));
                asm volatile("v_accvgpr_read_b32 %0, %1" : "=v"(w2) : "a"(aw[(q * 15 + m) * 4 + 2]));
                asm volatile("v_accvgpr_read_b32 %0, %1" : "=v"(w3) : "a"(aw[(q * 15 + m) * 4 + 3]));
                ah[q] = dot2(w0, Hhv.x, ah[q]);
                ah[q] = dot2(w1, Hhv.y, ah[q]);
                ah[q] = dot2(w2, Hhv.z, ah[q]);
                ah[q] = dot2(w3, Hhv.w, ah[q]);
            }
        }
        // ---- LDS region: kp 100..127 (g8 25..31) ----
        #pragma unroll
        for (int g = 0; g < 7; ++g) {
            const int g8 = 25 + g;
            uint4 Hhv = Hh[g8];
            #pragma unroll
            for (int q = 0; q < 4; ++q) {
                uint4 w = wlds4[(q * 7 + g) * 256 + tid];
                ah[q] = dot2(w.x, Hhv.x, ah[q]);
                ah[q] = dot2(w.y, Hhv.y, ah[q]);
                ah[q] = dot2(w.z, Hhv.z, ah[q]);
                ah[q] = dot2(w.w, Hhv.w, ah[q]);
            }
        }

        // ---- activation ----
        float z[4];
        #pragma unroll
        for (int q = 0; q < 4; ++q) z[q] = ah[q];
        if (LAYER == 0) {
            uint xph[6];
            #pragma unroll
            for (int d = 0; d < 6; ++d) xph[d] = pkrtz(xv[2 * d], xv[2 * d + 1]);
            #pragma unroll
            for (int q = 0; q < 4; ++q) {
                float a = bias[q];
                #pragma unroll
                for (int d = 0; d < 6; ++d)
                    a = dot2(wihl[(q * 6 + d) * 256 + tid], xph[d], a);
                z[q] += a;
            }
        } else {
            z[0] += xq4.x; z[1] += xq4.y; z[2] += xq4.z; z[3] += xq4.w;
        }
        cv = sigm(z[1]) * cv + sigm(z[0]) * tanh_(z[2]);
        hv = sigm(z[3]) * tanh_(cv);
        if (LAYER == 1) hsv += hv;

        f16 hi = (f16)hv;
        hs16[(par ^ 1) * 256 + tid] = hbits(hi);
        if (LAYER == 0) {
            const int t = dir ? (NT - 1 - it) : it;
            out0h[((size_t)b * NT + t) * 512 + dir * 256 + tid] = hi;
        }
        __syncthreads();
    }

    cst[sidx] = cv; hst[sidx] = hv;
    if (LAYER == 1) hsm[(dir * NB + b) * NH + tid] = hsv;
}

// ---------------------------------------------------------------------------
// proj_role (chunk c): fp16 MFMA 16x16x32 direct-from-global (layout verified
// rounds 6-7). 128 role-blocks x 4 waves; wave handles 2 m-tiles of the
// 1024 (dir x 512) m-tiles. Stores xp1 in [t][unit][gate] order so rec1's
// per-step gate fetch is a single coalesced float4.
// ---------------------------------------------------------------------------
__device__ void proj_role(int pb, int c,
                          const f16* __restrict__ out0h, const f16* __restrict__ wih1h,
                          const float* __restrict__ bsum1, float* __restrict__ xp1) {
    const int tid = threadIdx.x;
    const int w = tid >> 6, l = tid & 63;
    const int lane16 = l & 15, quad = l >> 4;

    #pragma unroll 1
    for (int mi = 0; mi < 2; ++mi) {
        const int mtg = pb * 8 + w * 2 + mi;       // 0..1023
        const int dirt = mtg >> 9;
        const int mtl = mtg & 511;

        const int ra = mtl * 16 + lane16;          // row over b(64) x tl(128)
        const int ab = ra >> 7, tla = ra & 127;
        const int ta = dirt ? (NT - 1 - c * TCL - tla) : (c * TCL + tla);
        const f16* Arow = out0h + ((size_t)ab * NT + ta) * 512 + quad * 8;

        uint4 afr[16];
        #pragma unroll
        for (int kt = 0; kt < 16; ++kt) afr[kt] = *(const uint4*)(Arow + kt * 32);

        int ob[4], otl[4];
        #pragma unroll
        for (int reg = 0; reg < 4; ++reg) {
            int rr = mtl * 16 + quad * 4 + reg;
            ob[reg] = rr >> 7; otl[reg] = rr & 127;
        }

        const f16* Bbase = wih1h + (size_t)dirt * NG * 512 + quad * 8;

        #pragma unroll 1
        for (int nt = 0; nt < 64; ++nt) {
            const int col = nt * 16 + lane16;
            const f16* Brow = Bbase + (size_t)col * 512;
            float bias = bsum1[dirt * NG + col];

            f32x4 acc = {0.f, 0.f, 0.f, 0.f};
            #pragma unroll
            for (int kt = 0; kt < 16; ++kt) {
                uint4 bv = *(const uint4*)(Brow + kt * 32);
                acc = __builtin_amdgcn_mfma_f32_16x16x32_f16(
                    __builtin_bit_cast(f16x8, afr[kt]),
                    __builtin_bit_cast(f16x8, bv), acc, 0, 0, 0);
            }
            const int ucol = col & 255, qcol = col >> 8;
            #pragma unroll
            for (int reg = 0; reg < 4; ++reg) {
                xp1[((size_t)(dirt * NB + ob[reg]) * TCL + otl[reg]) * NG
                    + ucol * 4 + qcol] = acc[reg] + bias;
            }
        }
    }
}

// ---------------------------------------------------------------------------
// Phase A: layer 0, full 1024 steps, 128 independent blocks.
// ---------------------------------------------------------------------------
__global__ __launch_bounds__(256, 1) void k_rec0(
    const uint* __restrict__ Wkv, const uint* __restrict__ Wka,
    const uint* __restrict__ Wkl, const uint* __restrict__ wih0p,
    const float* __restrict__ b_ih0, const float* __restrict__ b_hh0,
    const float* __restrict__ x, f16* __restrict__ out0h,
    float* __restrict__ hst, float* __restrict__ cst) {
    extern __shared__ __align__(16) char smem[];
    rec_seq<0>(smem, blockIdx.x, 0, NT, Wkv, Wka, Wkl, wih0p, b_ih0, b_hh0,
               x, nullptr, out0h, hst, cst, nullptr);
}

// ---------------------------------------------------------------------------
// Phase B launch j: blocks 0..127 = rec1 chunk j-1; blocks 128..255 = proj
// chunk j. Legal: proj depends only on out0h (complete after phase A);
// rec1(j-1) reads xp1 written by proj in launch j-1. Double-buffered xp1.
// ---------------------------------------------------------------------------
__global__ __launch_bounds__(256, 1) void k_pipe(
    int j,
    const uint* __restrict__ Wkv, const uint* __restrict__ Wka,
    const uint* __restrict__ Wkl,
    const f16* __restrict__ out0h, const f16* __restrict__ wih1h,
    const float* __restrict__ bsum1, float* __restrict__ xp1,
    float* __restrict__ hst, float* __restrict__ cst, float* __restrict__ hsm) {
    extern __shared__ __align__(16) char smem[];
    const int bid = blockIdx.x;
    if (bid < 128) {
        const int cc = j - 1;
        if (cc >= 0 && cc < NCHUNK)
            rec_seq<1>(smem, bid, cc, TCL, Wkv, Wka, Wkl, nullptr, nullptr, nullptr,
                       nullptr, xp1 + (size_t)(cc & 1) * XPS, nullptr, hst, cst, hsm);
    } else {
        const int cp = j;
        if (cp < NCHUNK)
            proj_role(bid - 128, cp, out0h, wih1h, bsum1,
                      xp1 + (size_t)(cp & 1) * XPS);
    }
}

// ---------------------------------------------------------------------------
__global__ void k_fc(const float* __restrict__ hsm, const float* __restrict__ fc_w,
                     const float* __restrict__ fc_b, float* __restrict__ out) {
    const int b = blockIdx.x;
    const int n = threadIdx.x;
    if (n >= NCLS) return;
    float acc = fc_b[n];
    const float inv = 1.0f / (float)NT;
    for (int k = 0; k < 2 * NH; ++k) {
        float pv = hsm[((k >> 8) * NB + b) * NH + (k & 255)];
        acc += (pv * inv) * fc_w[n * 2 * NH + k];
    }
    out[b * NCLS + n] = acc;
}

// ---------------------------------------------------------------------------
extern "C" void kernel_launch(void* const* d_in, const int* in_sizes, int n_in,
                              void* d_out, int out_size, void* d_ws, size_t ws_size,
                              hipStream_t stream) {
    const float* x     = (const float*)d_in[0];
    const float* w_ih0 = (const float*)d_in[1];
    const float* w_hh0 = (const float*)d_in[2];
    const float* b_ih0 = (const float*)d_in[3];
    const float* b_hh0 = (const float*)d_in[4];
    const float* w_ih1 = (const float*)d_in[5];
    const float* w_hh1 = (const float*)d_in[6];
    const float* b_ih1 = (const float*)d_in[7];
    const float* b_hh1 = (const float*)d_in[8];
    const float* fc_w  = (const float*)d_in[9];
    const float* fc_b  = (const float*)d_in[10];
    float* out = (float*)d_out;

    char* ws = (char*)d_ws;
    uint* Wkv   = (uint*)ws;                      // 163840 u
    uint* Wka   = Wkv + 163840;                   // 245760 u
    uint* Wkl   = Wka + 245760;                   // 114688 u
    uint* wih0p = Wkl + 114688;                   // 12288 u
    f16* wih1h  = (f16*)(wih0p + 12288);          // 1048576 h = 2 MB
    float* bsum1 = (float*)(wih1h + 1048576);     // 2048 f
    float* hst  = bsum1 + 2048;                   // 65536 f
    float* cst  = hst + 65536;                    // 65536 f
    float* hsm  = cst + 65536;                    // 32768 f
    float* xp1  = hsm + 32768;                    // 2 x 16777216 f = 128 MB
    f16* out0h  = (f16*)(xp1 + 2 * XPS);          // 33554432 h = 64 MB

    k_prep<<<dim3(4096), dim3(256), 0, stream>>>(
        w_hh0, w_hh1, w_ih0, w_ih1, b_ih1, b_hh1,
        Wkv, Wka, Wkl, wih0p, wih1h, bsum1);

    k_rec0<<<dim3(128), dim3(256), 140288, stream>>>(
        Wkv, Wka, Wkl, wih0p, b_ih0, b_hh0, x, out0h, hst, cst);

    for (int j = 0; j <= NCHUNK; ++j) {
        k_pipe<<<dim3(256), dim3(256), 115712, stream>>>(
            j, Wkv, Wka, Wkl, out0h, wih1h, bsum1, xp1, hst, cst, hsm);
    }

    k_fc<<<dim3(64), dim3(32), 0, stream>>>(hsm, fc_w, fc_b, out);
}